// Round 5
// baseline (537.778 us; speedup 1.0000x reference)
//
#include <hip/hip_runtime.h>
#include <hip/hip_cooperative_groups.h>

namespace cg = cooperative_groups;

typedef unsigned int u32;
typedef unsigned long long u64;

#define A_TOT    159882
#define BS       2
#define KTOP     1000
#define CAND_CAP 4096
#define NBLK     240
#define NTHR     256
#define GSIZE    (NBLK * NTHR)
#define EPT      6            // 240*256*6 = 368640 >= 319764

// ---- workspace layout (bytes) ----
static const size_t COARSE_OFF = 0;          // u32[8*256]
static const size_t FINE_OFF   = 8192;       // u32[8*256]
static const size_t CC_OFF     = 16384;      // u32[8]  coarse cut bucket
static const size_t CB_OFF     = 16416;      // u32[8]  count strictly below
static const size_t CUT_OFF    = 16448;      // u32[8]  16-bit cut
static const size_t CCNT_OFF   = 16480;      // u32[8]
static const size_t MAXC_OFF   = 16512;      // u32[2]
static const size_t CHUNKANY_OFF = 16576;    // u64[10*16]
static const size_t KB_OFF     = 17856;      // u64[2*128]
static const size_t ZERO_END   = 19904;
static const size_t NV_OFF     = 19968;      // u32[10] (always written)
static const size_t CAND_OFF   = 20480;      // u64[8*4096]
static const size_t LSORT_OFF  = 282624;     // u64[10*1024]
static const size_t DBOX_OFF   = 364544;     // float4[10*1024]
static const size_t DVAL_OFF   = 528384;     // u32[10*1024]
static const size_t DSC_OFF    = 569344;     // float[10*1024]
static const size_t LKEY2_OFF  = 610304;     // u64[10*1024]
static const size_t LBOX_OFF   = 692224;     // float4[10*1024]
static const size_t LSC_OFF    = 856064;     // float[10*1024]
static const size_t RANK_OFF   = 897024;     // u32[10*1024]
static const size_t GL_OFF     = 937984;     // u32[2*4608]
static const size_t MASK_OFF   = 974848;     // u64[10*16000]
// total ~2.15 MB

__device__ __forceinline__ int level_of(int a) {
  if (a < 120000) return 0;
  if (a < 150000) return 1;
  if (a < 157500) return 2;
  if (a < 159375) return 3;
  return 4;
}
__device__ __forceinline__ int level_n(int l) { return (l == 4) ? 507 : 1000; }

// monotone decreasing transform: smaller d == larger score; d(-inf)=0xFF800000
__device__ __forceinline__ u32 dkey(float s) {
  u32 b = __float_as_uint(s);
  return (b & 0x80000000u) ? b : (~b & 0x7FFFFFFFu);
}

// bit-exact replica of reference decode + clip + min-size check
__device__ __forceinline__ void decode_clip(const float* __restrict__ pred,
                                            const float* __restrict__ anch,
                                            const float* __restrict__ vs,
                                            int b, int a,
                                            float& x1c, float& y1c, float& x2c, float& y2c,
                                            bool& valid) {
  const float* pp = pred + ((size_t)b * A_TOT + (size_t)a) * 4;
  const float* aa = anch + (size_t)a * 4;
  float ax1 = aa[0], ay1 = aa[1], ax2 = aa[2], ay2 = aa[3];
  float px = pp[0], py = pp[1], pw = pp[2], ph = pp[3];
  float aw  = __fsub_rn(ax2, ax1);
  float ah  = __fsub_rn(ay2, ay1);
  float acx = __fadd_rn(ax1, __fmul_rn(0.5f, aw));
  float acy = __fadd_rn(ay1, __fmul_rn(0.5f, ah));
  float cx  = __fadd_rn(acx, __fmul_rn(px, aw));
  float cy  = __fadd_rn(acy, __fmul_rn(py, ah));
  float w   = __fmul_rn(expf(pw), aw);
  float h   = __fmul_rn(expf(ph), ah);
  float x1  = __fsub_rn(cx, __fmul_rn(0.5f, w));
  float y1  = __fsub_rn(cy, __fmul_rn(0.5f, h));
  float x2  = __fadd_rn(x1, w);
  float y2  = __fadd_rn(y1, h);
  float Wv = vs[b * 2 + 0], Hv = vs[b * 2 + 1];
  x1c = fminf(fmaxf(x1, 0.0f), Wv);
  y1c = fminf(fmaxf(y1, 0.0f), Hv);
  x2c = fminf(fmaxf(x2, 0.0f), Wv);
  y2c = fminf(fmaxf(y2, 0.0f), Hv);
  valid = (__fsub_rn(x2c, x1c) > 0.001f) && (__fsub_rn(y2c, y1c) > 0.001f);
}

__device__ __forceinline__ void bitonic_u64(u64* arr, int N, int t, int nt) {
  for (int k = 2; k <= N; k <<= 1) {
    for (int j = k >> 1; j > 0; j >>= 1) {
      __syncthreads();
      for (int i = t; i < N; i += nt) {
        int ixj = i ^ j;
        if (ixj > i) {
          u64 x = arr[i], y = arr[ixj];
          bool up = ((i & k) == 0);
          if (up ? (x > y) : (x < y)) { arr[i] = y; arr[ixj] = x; }
        }
      }
    }
  }
  __syncthreads();
}

__device__ __forceinline__ int lbound(const u64* __restrict__ arr, int n, u64 key) {
  int lo = 0, hi = n;
  while (lo < hi) { int mid = (lo + hi) >> 1; if (arr[mid] < key) lo = mid + 1; else hi = mid; }
  return lo;
}

__global__ __launch_bounds__(NTHR, 2)
void k_all(const float* __restrict__ pred, const float* __restrict__ obj,
           const float* __restrict__ anch, const float* __restrict__ vs,
           float* __restrict__ out, char* __restrict__ ws) {
  cg::grid_group grid = cg::this_grid();
  __shared__ u64 shbuf[CAND_CAP];     // 32 KB, reused per phase
  __shared__ u32 aux[32];
  u32* sh32 = (u32*)shbuf;
  const int tid = threadIdx.x;
  const int bid = blockIdx.x;
  const int gtid = bid * NTHR + tid;

  // ---- phase 0: zero control region ----
  for (size_t i = gtid; i * 4 < ZERO_END; i += GSIZE) ((u32*)ws)[i] = 0u;
  grid.sync();

  // ---- phase 1: coarse 8-bit histogram (LDS-privatized) ----
  {
    for (int i = tid; i < 2048; i += NTHR) sh32[i] = 0u;
    __syncthreads();
    int base_t = bid * (NTHR * EPT);
#pragma unroll
    for (int it = 0; it < EPT; ++it) {
      int t = base_t + it * NTHR + tid;
      if (t < BS * A_TOT) {
        int b = t / A_TOT, a = t % A_TOT;
        int l = level_of(a);
        if (l < 4) {
          u32 d = dkey(obj[t]);
          atomicAdd(&sh32[(u32)(b * 4 + l) * 256 + (d >> 24)], 1u);
        }
      }
    }
    __syncthreads();
    for (int i = tid; i < 2048; i += NTHR) {
      u32 v = sh32[i];
      if (v) atomicAdd((u32*)(ws + COARSE_OFF) + i, v);
    }
  }
  grid.sync();

  // ---- phase 2: coarse cutoff (blocks 0-7) ----
  if (bid < 8) {
    int seg = bid;
    u32 v = ((const u32*)(ws + COARSE_OFF))[seg * 256 + tid];
    sh32[tid] = v; __syncthreads();
    for (int d = 1; d < 256; d <<= 1) {
      u32 x = (tid >= d) ? sh32[tid - d] : 0u; __syncthreads();
      sh32[tid] += x; __syncthreads();
    }
    if (sh32[tid] >= KTOP && (tid == 0 || sh32[tid - 1] < KTOP)) {
      ((u32*)(ws + CC_OFF))[seg] = (u32)tid;
      ((u32*)(ws + CB_OFF))[seg] = (tid == 0) ? 0u : sh32[tid - 1];
    }
  }
  grid.sync();

  // ---- phase 3: fine 8-bit refine histogram ----
  {
    int base_t = bid * (NTHR * EPT);
#pragma unroll
    for (int it = 0; it < EPT; ++it) {
      int t = base_t + it * NTHR + tid;
      if (t < BS * A_TOT) {
        int b = t / A_TOT, a = t % A_TOT;
        int l = level_of(a);
        if (l < 4) {
          u32 seg = (u32)(b * 4 + l);
          u32 d = dkey(obj[t]);
          if ((d >> 24) == ((const u32*)(ws + CC_OFF))[seg])
            atomicAdd((u32*)(ws + FINE_OFF) + seg * 256 + ((d >> 16) & 0xFFu), 1u);
        }
      }
    }
  }
  grid.sync();

  // ---- phase 4: fine cutoff -> 16-bit cut (blocks 0-7) ----
  if (bid < 8) {
    int seg = bid;
    u32 cb = ((const u32*)(ws + CB_OFF))[seg];
    u32 cc = ((const u32*)(ws + CC_OFF))[seg];
    u32 v = ((const u32*)(ws + FINE_OFF))[seg * 256 + tid];
    sh32[tid] = v; __syncthreads();
    for (int d = 1; d < 256; d <<= 1) {
      u32 x = (tid >= d) ? sh32[tid - d] : 0u; __syncthreads();
      sh32[tid] += x; __syncthreads();
    }
    if (cb + sh32[tid] >= KTOP && (tid == 0 || cb + sh32[tid - 1] < KTOP))
      ((u32*)(ws + CUT_OFF))[seg] = (cc << 8) | (u32)tid;
  }
  grid.sync();

  // ---- phase 5: compact candidates (block-aggregated allocation) ----
  {
    u32* lcnt = aux; u32* gbase = aux + 8; u32* lcut = aux + 16;
    if (tid < 8) { lcnt[tid] = 0; lcut[tid] = ((const u32*)(ws + CUT_OFF))[tid]; }
    __syncthreads();
    int lane = tid & 63;
    int base_t = bid * (NTHR * EPT);
    u32 dv[EPT], slotv[EPT], passmask = 0;
#pragma unroll
    for (int it = 0; it < EPT; ++it) {
      int t = base_t + it * NTHR + tid;
      bool pass = false; u32 seg = 0, d = 0;
      if (t < BS * A_TOT) {
        int b = t / A_TOT, a = t % A_TOT;
        int l = level_of(a);
        if (l < 4) {
          seg = (u32)(b * 4 + l);
          d = dkey(obj[t]);
          pass = (d >> 16) <= lcut[seg];
        }
      }
      dv[it] = d;
      u32 slot = 0;
      u64 rem = __ballot(pass);
      while (rem) {
        int ld = __builtin_ctzll(rem);
        u32 s0 = __shfl(seg, ld);
        u64 grp = __ballot(pass && seg == s0);
        u32 wb = 0;
        if (lane == ld) wb = atomicAdd(&lcnt[s0], (u32)__popcll(grp));
        wb = __shfl(wb, ld);
        if (pass && seg == s0)
          slot = wb + (u32)__popcll(grp & ((1ull << lane) - 1ull));
        rem &= ~grp;
      }
      slotv[it] = slot;
      if (pass) passmask |= (1u << it);
    }
    __syncthreads();
    if (tid < 8)
      gbase[tid] = lcnt[tid] ? atomicAdd((u32*)(ws + CCNT_OFF) + tid, lcnt[tid]) : 0u;
    __syncthreads();
#pragma unroll
    for (int it = 0; it < EPT; ++it) {
      if ((passmask >> it) & 1u) {
        int t = base_t + it * NTHR + tid;
        int b = t / A_TOT, a = t % A_TOT;
        int l = level_of(a);
        u32 seg = (u32)(b * 4 + l);
        u32 gslot = gbase[seg] + slotv[it];
        if (gslot < CAND_CAP)
          ((u64*)(ws + CAND_OFF))[(size_t)seg * CAND_CAP + gslot] =
              ((u64)dv[it] << 32) | (u32)a;
      }
    }
  }
  grid.sync();

  // ---- phase 6: per-(image,level) sorted key lists (blocks 0-9) ----
  if (bid < 10) {
    int P = bid, b = P / 5, l = P % 5;
    int N, n_out;
    if (l < 4) {
      u32 cnt = ((const u32*)(ws + CCNT_OFF))[b * 4 + l];
      if (cnt > CAND_CAP) cnt = CAND_CAP;
      N = 1024; while (N < (int)cnt) N <<= 1;
      const u64* cand = (const u64*)(ws + CAND_OFF) + (size_t)(b * 4 + l) * CAND_CAP;
      for (int i = tid; i < N; i += NTHR) shbuf[i] = (i < (int)cnt) ? cand[i] : ~0ull;
      n_out = KTOP;
    } else {
      N = 512;
      for (int i = tid; i < N; i += NTHR) {
        if (i < 507) {
          int a = 159375 + i;
          u32 d = dkey(obj[(size_t)b * A_TOT + a]);
          shbuf[i] = ((u64)d << 32) | (u32)a;
        } else shbuf[i] = ~0ull;
      }
      n_out = 507;
    }
    bitonic_u64(shbuf, N, tid, NTHR);
    u64* lsort = (u64*)(ws + LSORT_OFF) + (size_t)P * 1024;
    for (int i = tid; i < n_out; i += NTHR) lsort[i] = shbuf[i];
  }
  grid.sync();

  // ---- phase 7: decode + stable valid-compaction (blocks 0-9) ----
  if (bid < 10) {
    int P = bid, b = P / 5, l = P % 5;
    int n = level_n(l);
    float m = 0.0f;
    for (int j = tid; j < 1024; j += NTHR) {
      if (j < n) {
        u64 key = ((const u64*)(ws + LSORT_OFF))[(size_t)P * 1024 + j];
        int a = (int)(u32)key;
        float x1, y1, x2, y2; bool valid;
        decode_clip(pred, anch, vs, b, a, x1, y1, x2, y2, valid);
        m = fmaxf(m, fmaxf(fmaxf(x1, y1), fmaxf(x2, y2)));
        ((float4*)(ws + DBOX_OFF))[(size_t)P * 1024 + j] = make_float4(x1, y1, x2, y2);
        ((u32*)(ws + DVAL_OFF))[(size_t)P * 1024 + j] = valid ? 1u : 0u;
        ((float*)(ws + DSC_OFF))[(size_t)P * 1024 + j] = obj[(size_t)b * A_TOT + a];
      }
    }
    for (int off = 32; off; off >>= 1) m = fmaxf(m, __shfl_xor(m, off));
    if ((tid & 63) == 0) atomicMax((u32*)(ws + MAXC_OFF) + b, __float_as_uint(m));
    __syncthreads();
    if (tid < 64) {                       // wave 0: sequential compaction
      int lane = tid, base = 0;
      for (int j0 = 0; j0 < n; j0 += 64) {
        int j = j0 + lane;
        bool inb = j < n;
        u32 v = inb ? ((const u32*)(ws + DVAL_OFF))[(size_t)P * 1024 + j] : 0u;
        u64 mm = __ballot(v != 0);
        int r = base + __popcll(mm & ((1ull << lane) - 1ull));
        if (v) {
          ((u64*)(ws + LKEY2_OFF))[(size_t)P * 1024 + r] =
              ((const u64*)(ws + LSORT_OFF))[(size_t)P * 1024 + j];
          ((float4*)(ws + LBOX_OFF))[(size_t)P * 1024 + r] =
              ((const float4*)(ws + DBOX_OFF))[(size_t)P * 1024 + j];
          ((float*)(ws + LSC_OFF))[(size_t)P * 1024 + r] =
              ((const float*)(ws + DSC_OFF))[(size_t)P * 1024 + j];
        }
        base += __popcll(mm);
      }
      if (lane == 0) ((u32*)(ws + NV_OFF))[P] = (u32)base;
    }
  }
  grid.sync();

  // ---- phase 8: global rank via 5-way merge (blocks 0-9) ----
  if (bid < 10) {
    int P = bid, b = P / 5, l = P % 5;
    int nv = (int)((const u32*)(ws + NV_OFF))[P];
    const u64* lkey = (const u64*)(ws + LKEY2_OFF);
    const u32* nvp = (const u32*)(ws + NV_OFF);
    for (int i = tid; i < nv; i += NTHR) {
      u64 key = lkey[(size_t)P * 1024 + i];
      int r = i;
      for (int l2 = 0; l2 < 5; ++l2) {
        if (l2 == l) continue;
        int P2 = b * 5 + l2;
        r += lbound(lkey + (size_t)P2 * 1024, (int)nvp[P2], key);
      }
      ((u32*)(ws + RANK_OFF))[(size_t)P * 1024 + i] = (u32)r;
      ((u32*)(ws + GL_OFF))[(size_t)b * 4608 + r] = ((u32)l << 16) | (u32)i;
    }
  }
  grid.sync();

  // ---- phase 9: suppression bitmask (grid-stride) ----
  for (int idx = gtid; idx < 163840; idx += GSIZE) {
    int w = idx & 15;
    int i = (idx >> 4) & 1023;
    int P = idx >> 14;
    int b = P / 5, l = P % 5;
    int n = (int)((const u32*)(ws + NV_OFF))[P];
    int W = (n + 63) >> 6;
    if (i >= n || w >= W) continue;
    float M = __uint_as_float(((const u32*)(ws + MAXC_OFF))[b]);
    float maxc = __fadd_rn(M, 1.0f);
    float off = __fmul_rn((float)l, maxc);
    const float4* lbox = (const float4*)(ws + LBOX_OFF) + (size_t)P * 1024;
    float4 bi = lbox[i];
    bi.x = __fadd_rn(bi.x, off); bi.y = __fadd_rn(bi.y, off);
    bi.z = __fadd_rn(bi.z, off); bi.w = __fadd_rn(bi.w, off);
    float ai = __fmul_rn(__fsub_rn(bi.z, bi.x), __fsub_rn(bi.w, bi.y));
    u64 word = 0;
    int j0 = w << 6;
    int jn = min(64, n - j0);
    for (int jj = 0; jj < jn; ++jj) {
      float4 bj = lbox[j0 + jj];
      bj.x = __fadd_rn(bj.x, off); bj.y = __fadd_rn(bj.y, off);
      bj.z = __fadd_rn(bj.z, off); bj.w = __fadd_rn(bj.w, off);
      float xx1 = fmaxf(bi.x, bj.x);
      float yy1 = fmaxf(bi.y, bj.y);
      float xx2 = fminf(bi.z, bj.z);
      float yy2 = fminf(bi.w, bj.w);
      float iw = fmaxf(__fsub_rn(xx2, xx1), 0.0f);
      float ih = fmaxf(__fsub_rn(yy2, yy1), 0.0f);
      float inter = __fmul_rn(iw, ih);
      float aj = __fmul_rn(__fsub_rn(bj.z, bj.x), __fsub_rn(bj.w, bj.y));
      float den = __fadd_rn(__fsub_rn(__fadd_rn(ai, aj), inter), 1e-9f);
      float iou = __fdiv_rn(inter, den);
      if (iou > 0.7f) word |= (1ull << jj);
    }
    if (i >= j0 && i < j0 + 64) word &= ~(1ull << (i - j0));   // zero diagonal
    ((u64*)(ws + MASK_OFF))[(size_t)P * 16000 + (size_t)i * W + w] = word;
    if (word)
      atomicOr((u64*)(ws + CHUNKANY_OFF) + (size_t)P * 16 + (i >> 6), 1ull << (i & 63));
  }
  grid.sync();

  // ---- phase 10: chunked greedy scan (blocks 0-9, wave 0) ----
  if (bid < 10) {
    int P = bid, b = P / 5;
    int n = (int)((const u32*)(ws + NV_OFF))[P];
    int W = (n + 63) >> 6;
    if (tid < 64) {
      int lane = tid;
      const u64* maskg = (const u64*)(ws + MASK_OFF) + (size_t)P * 16000;
      const u64* chunkany = (const u64*)(ws + CHUNKANY_OFF) + (size_t)P * 16;
      u64 removed = 0, keepw = 0;
      int NC = (n + 63) >> 6;
      for (int c = 0; c < NC; ++c) {
        int rb = c << 6;
        int rows = min(64, n - rb);
        u64 rowsmask = (rows == 64) ? ~0ull : ((1ull << rows) - 1ull);
        u64 curw = __shfl(removed, c);
        u64 cand = ~curw & rowsmask;
        u64 anyrows = chunkany[c] & cand;
        u64 keptbits;
        if (anyrows == 0ull) {
          keptbits = cand;
        } else {
          u64 diag = (lane < rows) ? maskg[(size_t)(rb + lane) * W + c] : 0ull;
          u64 diagnz = __ballot(diag != 0ull);
          if ((diagnz & cand) == 0ull) {
            keptbits = cand;
          } else {
            u64 remw = curw | ~rowsmask;
            u64 kept = 0;
            for (int r = 0; r < rows; ++r) {
              u64 dr = __shfl(diag, r);
              bool k = ((remw >> r) & 1ull) == 0ull;
              u64 sel = k ? ~0ull : 0ull;
              remw |= dr & sel;
              kept |= ((u64)(k ? 1 : 0)) << r;
            }
            keptbits = kept;
          }
          u64 todo = keptbits & chunkany[c];
          while (todo) {
            int r = __builtin_ctzll(todo);
            todo &= todo - 1;
            u64 rowv = (lane < W) ? maskg[(size_t)(rb + r) * W + lane] : 0ull;
            removed |= rowv;
          }
        }
        if (lane == c) keepw |= keptbits;
      }
      if (lane < 16) shbuf[lane] = keepw;
    }
    __syncthreads();
    const u32* rank = (const u32*)(ws + RANK_OFF) + (size_t)P * 1024;
    for (int i = tid; i < n; i += NTHR) {
      if ((shbuf[i >> 6] >> (i & 63)) & 1ull) {
        u32 r = rank[i];
        atomicOr((u64*)(ws + KB_OFF) + (size_t)b * 128 + (r >> 6), 1ull << (r & 63));
      }
    }
  }
  grid.sync();

  // ---- phase 11: zero-fill out; prefix-popcount emit (blocks 0-1) ----
  if (bid < 2) {
    int b = bid;
    for (int i = tid; i < 4000; i += NTHR) out[(size_t)b * 4000 + i] = 0.0f;
    for (int i = tid; i < 1000; i += NTHR) out[8000 + (size_t)b * 1000 + i] = 0.0f;
    if (tid < 72) shbuf[tid] = ((const u64*)(ws + KB_OFF))[(size_t)b * 128 + tid];
    __syncthreads();
    if (tid < 64) {
      int lane = tid, base = 0;
      for (int w = 0; w < 72; ++w) {
        u64 word = shbuf[w];
        bool mine = (word >> lane) & 1ull;
        int slot = base + __popcll(word & ((1ull << lane) - 1ull));
        if (mine && slot < KTOP) {
          int r = w * 64 + lane;
          u32 g = ((const u32*)(ws + GL_OFF))[(size_t)b * 4608 + r];
          int l = g >> 16, i = g & 0xFFFF;
          int P = b * 5 + l;
          float4 bx = ((const float4*)(ws + LBOX_OFF))[(size_t)P * 1024 + i];
          float s = ((const float*)(ws + LSC_OFF))[(size_t)P * 1024 + i];
          float* ob = out + ((size_t)b * KTOP + slot) * 4;
          ob[0] = bx.x; ob[1] = bx.y; ob[2] = bx.z; ob[3] = bx.w;
          out[8000 + (size_t)b * KTOP + slot] = s;
        }
        base += __popcll(word);
      }
    }
  }
}

extern "C" void kernel_launch(void* const* d_in, const int* in_sizes, int n_in,
                              void* d_out, int out_size, void* d_ws, size_t ws_size,
                              hipStream_t stream) {
  const float* pred = (const float*)d_in[0];
  const float* obj  = (const float*)d_in[1];
  const float* anch = (const float*)d_in[2];
  const float* vs   = (const float*)d_in[3];
  float* out = (float*)d_out;
  char* ws = (char*)d_ws;
  (void)in_sizes; (void)n_in; (void)out_size; (void)ws_size;

  void* kargs[] = {(void*)&pred, (void*)&obj, (void*)&anch, (void*)&vs,
                   (void*)&out, (void*)&ws};
  hipLaunchCooperativeKernel((const void*)k_all, dim3(NBLK), dim3(NTHR),
                             kargs, 0, stream);
}

// Round 6
// 223.880 us; speedup vs baseline: 2.4021x; 2.4021x over previous
//
#include <hip/hip_runtime.h>

typedef unsigned int u32;
typedef unsigned long long u64;

#define A_TOT    159882
#define BS       2
#define KTOP     1000
#define CAND_CAP 4096
#define HB       4096        // 12-bit histogram buckets per segment
#define ABLK     4096        // anchors per hist/compact block
#define NBH      40          // blocks per image (40*4096 >= A_TOT)
#define EPT      16          // ABLK/256

// ---- workspace layout (bytes) ----
static const size_t HIST12_OFF   = 0;         // u32[8*4096] = 128 KB (L2-resident)
static const size_t CUT_OFF      = 131072;    // u32[8]
static const size_t CCNT_OFF     = 131104;    // u32[8]
static const size_t MAXC_OFF     = 131136;    // u32[2]
static const size_t NV_OFF       = 131144;    // u32[10]
static const size_t CHUNKANY_OFF = 131200;    // u64[10*16]
static const size_t ZERO_END     = 132480;    // k_zero covers [0, ZERO_END)
static const size_t CAND_OFF     = 132480;    // u64[8*4096]
static const size_t LKEY2_OFF    = 394624;    // u64[10*1024]
static const size_t LBOX_OFF     = 476544;    // float4[10*1024]
static const size_t LSC_OFF      = 640384;    // float[10*1024]
static const size_t RANK_OFF     = 681344;    // u32[10*1024]
static const size_t GL_OFF       = 722304;    // u32[2*4608]
static const size_t MASK_OFF     = 759168;    // u64[10*16000]
// total ~2.04 MB

__device__ __forceinline__ int level_of(int a) {
  if (a < 120000) return 0;
  if (a < 150000) return 1;
  if (a < 157500) return 2;
  if (a < 159375) return 3;
  return 4;
}

// monotone decreasing transform: smaller d == larger score; d(-inf)=0xFF800000
__device__ __forceinline__ u32 dkey(float s) {
  u32 b = __float_as_uint(s);
  return (b & 0x80000000u) ? b : (~b & 0x7FFFFFFFu);
}

// bit-exact replica of reference decode + clip + min-size check
__device__ __forceinline__ void decode_clip(const float* __restrict__ pred,
                                            const float* __restrict__ anch,
                                            const float* __restrict__ vs,
                                            int b, int a,
                                            float& x1c, float& y1c, float& x2c, float& y2c,
                                            bool& valid) {
  const float* pp = pred + ((size_t)b * A_TOT + (size_t)a) * 4;
  const float* aa = anch + (size_t)a * 4;
  float ax1 = aa[0], ay1 = aa[1], ax2 = aa[2], ay2 = aa[3];
  float px = pp[0], py = pp[1], pw = pp[2], ph = pp[3];
  float aw  = __fsub_rn(ax2, ax1);
  float ah  = __fsub_rn(ay2, ay1);
  float acx = __fadd_rn(ax1, __fmul_rn(0.5f, aw));
  float acy = __fadd_rn(ay1, __fmul_rn(0.5f, ah));
  float cx  = __fadd_rn(acx, __fmul_rn(px, aw));
  float cy  = __fadd_rn(acy, __fmul_rn(py, ah));
  float w   = __fmul_rn(expf(pw), aw);
  float h   = __fmul_rn(expf(ph), ah);
  float x1  = __fsub_rn(cx, __fmul_rn(0.5f, w));
  float y1  = __fsub_rn(cy, __fmul_rn(0.5f, h));
  float x2  = __fadd_rn(x1, w);
  float y2  = __fadd_rn(y1, h);
  float Wv = vs[b * 2 + 0], Hv = vs[b * 2 + 1];
  x1c = fminf(fmaxf(x1, 0.0f), Wv);
  y1c = fminf(fmaxf(y1, 0.0f), Hv);
  x2c = fminf(fmaxf(x2, 0.0f), Wv);
  y2c = fminf(fmaxf(y2, 0.0f), Hv);
  valid = (__fsub_rn(x2c, x1c) > 0.001f) && (__fsub_rn(y2c, y1c) > 0.001f);
}

__device__ __forceinline__ void bitonic_u64(u64* arr, int N, int t, int nt) {
  for (int k = 2; k <= N; k <<= 1) {
    for (int j = k >> 1; j > 0; j >>= 1) {
      __syncthreads();
      for (int i = t; i < N; i += nt) {
        int ixj = i ^ j;
        if (ixj > i) {
          u64 x = arr[i], y = arr[ixj];
          bool up = ((i & k) == 0);
          if (up ? (x > y) : (x < y)) { arr[i] = y; arr[ixj] = x; }
        }
      }
    }
  }
  __syncthreads();
}

__device__ __forceinline__ int lbound(const u64* __restrict__ arr, int n, u64 key) {
  int lo = 0, hi = n;
  while (lo < hi) { int mid = (lo + hi) >> 1; if (arr[mid] < key) lo = mid + 1; else hi = mid; }
  return lo;
}

// ---------- 1) zero control + histogram region ----------
__global__ void k_zero(char* __restrict__ ws) {
  size_t i = (size_t)blockIdx.x * blockDim.x + threadIdx.x;
  if (i * 4 < ZERO_END) ((u32*)ws)[i] = 0u;
}

// ---------- 2) 12-bit histogram, LDS-privatized (<=2 segments/block) ----------
__global__ void k_hist12(const float* __restrict__ obj, char* __restrict__ ws) {
  __shared__ u32 h[2 * HB];   // 32 KB
  int tid = threadIdx.x;
  int b = blockIdx.x / NBH, loc = blockIdx.x % NBH;
  int start = loc * ABLK;
  int l0 = level_of(start);
  if (l0 >= 4) return;
  for (int i = tid; i < 2 * HB; i += 256) h[i] = 0u;
  __syncthreads();
  for (int it = 0; it < EPT; ++it) {
    int a = start + it * 256 + tid;
    if (a < A_TOT) {
      int l = level_of(a);
      if (l < 4) {
        u32 d = dkey(obj[(size_t)b * A_TOT + a]);
        atomicAdd(&h[(u32)(l - l0) * HB + (d >> 20)], 1u);
      }
    }
  }
  __syncthreads();
  int lend = level_of(min(start + ABLK - 1, A_TOT - 1));
  int nseg = ((l0 + 1 <= lend) && (l0 + 1 < 4)) ? 2 : 1;
  for (int s = 0; s < nseg; ++s) {
    u32* gh = (u32*)(ws + HIST12_OFF) + (size_t)(b * 4 + l0 + s) * HB;
    for (int i = tid; i < HB; i += 256) {
      u32 v = h[s * HB + i];
      if (v) atomicAdd(&gh[i], v);
    }
  }
}

// ---------- 3) inline cutoff + block-aggregated candidate append ----------
__global__ void k_compactsel(const float* __restrict__ obj, char* __restrict__ ws) {
  __shared__ u32 scan[256];
  __shared__ u32 cutv[2];
  __shared__ u32 lcnt[2], gbase[2];
  int tid = threadIdx.x, lane = tid & 63;
  int b = blockIdx.x / NBH, loc = blockIdx.x % NBH;
  int start = loc * ABLK;
  int l0 = level_of(start);
  if (l0 >= 4) return;
  int lend = level_of(min(start + ABLK - 1, A_TOT - 1));
  int nseg = ((l0 + 1 <= lend) && (l0 + 1 < 4)) ? 2 : 1;
  if (tid < 2) lcnt[tid] = 0;
  // recompute segment cutoffs from L2-resident hist (idempotent across blocks)
  for (int s = 0; s < nseg; ++s) {
    int seg = b * 4 + l0 + s;
    const u32* gh = (const u32*)(ws + HIST12_OFF) + (size_t)seg * HB;
    u32 vals[16]; u32 acc = 0;
    for (int q = 0; q < 16; ++q) { vals[q] = gh[tid * 16 + q]; acc += vals[q]; }
    __syncthreads();
    scan[tid] = acc; __syncthreads();
    for (int d = 1; d < 256; d <<= 1) {
      u32 x = (tid >= d) ? scan[tid - d] : 0u; __syncthreads();
      scan[tid] += x; __syncthreads();
    }
    u32 incl = scan[tid], prev = incl - acc;
    if (prev < KTOP && incl >= KTOP) {
      u32 run = prev; int cb = HB - 1;
      for (int q = 0; q < 16; ++q) { run += vals[q]; if (run >= KTOP) { cb = tid * 16 + q; break; } }
      cutv[s] = (u32)cb;
      ((u32*)(ws + CUT_OFF))[seg] = (u32)cb;
    }
  }
  __syncthreads();
  u32 dv[EPT], slotv[EPT], passm = 0, sim = 0;
  for (int it = 0; it < EPT; ++it) {
    int a = start + it * 256 + tid;
    bool pass = false; u32 si = 0, d = 0;
    if (a < A_TOT) {
      int l = level_of(a);
      if (l < 4) {
        si = (u32)(l - l0);
        d = dkey(obj[(size_t)b * A_TOT + a]);
        pass = (d >> 20) <= cutv[si];
      }
    }
    dv[it] = d;
    u64 mp = __ballot(pass);
    u64 m1 = __ballot(pass && si == 1);
    u64 m0 = mp & ~m1;
    u32 slot = 0;
    if (m0) {
      int ld = __builtin_ctzll(m0);
      u32 wb = 0;
      if (lane == ld) wb = atomicAdd(&lcnt[0], (u32)__popcll(m0));
      wb = __shfl(wb, ld);
      if (pass && si == 0) slot = wb + (u32)__popcll(m0 & ((1ull << lane) - 1ull));
    }
    if (m1) {
      int ld = __builtin_ctzll(m1);
      u32 wb = 0;
      if (lane == ld) wb = atomicAdd(&lcnt[1], (u32)__popcll(m1));
      wb = __shfl(wb, ld);
      if (pass && si == 1) slot = wb + (u32)__popcll(m1 & ((1ull << lane) - 1ull));
    }
    slotv[it] = slot;
    if (pass) { passm |= 1u << it; if (si) sim |= 1u << it; }
  }
  __syncthreads();
  if (tid < 2)
    gbase[tid] = lcnt[tid] ? atomicAdd((u32*)(ws + CCNT_OFF) + (b * 4 + l0 + tid), lcnt[tid]) : 0u;
  __syncthreads();
  for (int it = 0; it < EPT; ++it) {
    if ((passm >> it) & 1u) {
      int a = start + it * 256 + tid;
      u32 si = (sim >> it) & 1u;
      int seg = b * 4 + l0 + (int)si;
      u32 gslot = gbase[si] + slotv[it];
      if (gslot < CAND_CAP)
        ((u64*)(ws + CAND_OFF))[(size_t)seg * CAND_CAP + gslot] =
            ((u64)dv[it] << 32) | (u32)a;
    }
  }
}

// ---------- 4) per-(image,level): 20-bit refine + sort + decode + compaction ----------
__global__ void k_sortdec(const float* __restrict__ pred, const float* __restrict__ obj,
                          const float* __restrict__ anch, const float* __restrict__ vs,
                          char* __restrict__ ws) {
  __shared__ u64 arr[CAND_CAP];       // 32 KB
  __shared__ float4 dboxL[1024];      // 16 KB
  __shared__ float dscL[1024];        // 4 KB
  __shared__ u64 vmask[16];
  __shared__ u32 h8[256];
  __shared__ u32 auxv[4];             // [0]=cnt_below [1]=append pos [2]=cut20 [3]=sel_total
  int tid = threadIdx.x, lane = tid & 63, wv = tid >> 6;
  int P = blockIdx.x, b = P / 5, l = P % 5;
  int n;
  if (l == 4) {
    n = 507;
    for (int i = tid; i < 512; i += 256) {
      u64 v = ~0ull;
      if (i < 507) { int a = 159375 + i; v = ((u64)dkey(obj[(size_t)b * A_TOT + a]) << 32) | (u32)a; }
      arr[i] = v;
    }
    bitonic_u64(arr, 512, tid, 256);
  } else {
    n = KTOP;
    int seg = b * 4 + l;
    u32 cnt = min(((const u32*)(ws + CCNT_OFF))[seg], (u32)CAND_CAP);
    u32 cut12 = ((const u32*)(ws + CUT_OFF))[seg];
    const u64* cand = (const u64*)(ws + CAND_OFF) + (size_t)seg * CAND_CAP;
    int N;
    if (cnt <= 2048) {
      u64 ev[8];
      for (int j = 0; j < 8; ++j) { int idx = j * 256 + tid; ev[j] = (idx < (int)cnt) ? cand[idx] : ~0ull; }
      h8[tid] = 0;
      if (tid < 4) auxv[tid] = 0;
      __syncthreads();
      u32 myb = 0;
      for (int j = 0; j < 8; ++j) {
        int idx = j * 256 + tid;
        if (idx < (int)cnt) {
          u32 b12 = (u32)(ev[j] >> 52);
          if (b12 < cut12) myb++;
          else atomicAdd(&h8[(u32)(ev[j] >> 44) & 0xFFu], 1u);
        }
      }
      for (int off = 32; off; off >>= 1) myb += __shfl_xor(myb, off);
      if (lane == 0) atomicAdd(&auxv[0], myb);
      __syncthreads();
      u32 cntb = auxv[0];
      u32 hv = h8[tid];
      __syncthreads();
      for (int d = 1; d < 256; d <<= 1) {
        u32 x = (tid >= d) ? h8[tid - d] : 0u; __syncthreads();
        h8[tid] += x; __syncthreads();
      }
      u32 incl = h8[tid], excl = incl - hv;
      if (cntb + incl >= KTOP && cntb + excl < KTOP) { auxv[2] = (u32)tid; auxv[3] = cntb + incl; }
      __syncthreads();
      u32 cut20 = auxv[2]; u32 selt = auxv[3];
      for (int i = tid; i < 2048; i += 256) arr[i] = ~0ull;
      __syncthreads();
      for (int j = 0; j < 8; ++j) {
        int idx = j * 256 + tid;
        if (idx < (int)cnt) {
          u32 b12 = (u32)(ev[j] >> 52);
          bool sel = (b12 < cut12) || (((u32)(ev[j] >> 44) & 0xFFu) <= cut20);
          if (sel) { u32 p = atomicAdd(&auxv[1], 1u); arr[p] = ev[j]; }
        }
      }
      __syncthreads();
      N = 1024; while (N < (int)selt) N <<= 1;
    } else {
      for (int i = tid; i < CAND_CAP; i += 256) arr[i] = (i < (int)cnt) ? cand[i] : ~0ull;
      N = 1024; while (N < (int)cnt) N <<= 1;
    }
    bitonic_u64(arr, N, tid, 256);
  }
  // decode + per-image max coord
  float m = 0.0f;
  for (int k = 0; k < 4; ++k) {
    int j = k * 256 + tid;
    bool vb = false;
    if (j < n) {
      u64 key = arr[j];
      int a = (int)(u32)key;
      float x1, y1, x2, y2; bool valid;
      decode_clip(pred, anch, vs, b, a, x1, y1, x2, y2, valid);
      m = fmaxf(m, fmaxf(fmaxf(x1, y1), fmaxf(x2, y2)));
      dboxL[j] = make_float4(x1, y1, x2, y2);
      dscL[j] = obj[(size_t)b * A_TOT + a];
      vb = valid;
    }
    u64 bal = __ballot(vb);
    if (lane == 0) vmask[k * 4 + wv] = bal;
  }
  for (int off = 32; off; off >>= 1) m = fmaxf(m, __shfl_xor(m, off));
  if (lane == 0) atomicMax((u32*)(ws + MAXC_OFF) + b, __float_as_uint(m));
  __syncthreads();
  // stable valid-compaction (wave 0)
  if (tid < 64) {
    int base = 0;
    for (int j0 = 0; j0 < n; j0 += 64) {
      int j = j0 + lane;
      bool v = (j < n) && ((vmask[j0 >> 6] >> lane) & 1ull);
      u64 mm = __ballot(v);
      int r = base + __popcll(mm & ((1ull << lane) - 1ull));
      if (v) {
        ((u64*)(ws + LKEY2_OFF))[(size_t)P * 1024 + r] = arr[j];
        ((float4*)(ws + LBOX_OFF))[(size_t)P * 1024 + r] = dboxL[j];
        ((float*)(ws + LSC_OFF))[(size_t)P * 1024 + r] = dscL[j];
      }
      base += __popcll(mm);
    }
    if (lane == 0) ((u32*)(ws + NV_OFF))[P] = (u32)base;
  }
}

// ---------- 5) rank (blocks 0-9) + suppression bitmask (all blocks) ----------
__global__ void k_maskrank(char* __restrict__ ws) {
  int tid = threadIdx.x, bid = blockIdx.x;
  if (bid < 10) {
    int P = bid, b = P / 5, l = P % 5;
    int nv = (int)((const u32*)(ws + NV_OFF))[P];
    const u64* lkey = (const u64*)(ws + LKEY2_OFF);
    const u32* nvp = (const u32*)(ws + NV_OFF);
    for (int i = tid; i < nv; i += 256) {
      u64 key = lkey[(size_t)P * 1024 + i];
      int r = i;
      for (int l2 = 0; l2 < 5; ++l2) {
        if (l2 == l) continue;
        int P2 = b * 5 + l2;
        r += lbound(lkey + (size_t)P2 * 1024, (int)nvp[P2], key);
      }
      ((u32*)(ws + RANK_OFF))[(size_t)P * 1024 + i] = (u32)r;
      ((u32*)(ws + GL_OFF))[(size_t)b * 4608 + r] = ((u32)l << 16) | (u32)i;
    }
  }
  int idx = bid * 256 + tid;       // 640*256 = 163840 items
  int w = idx & 15;
  int i = (idx >> 4) & 1023;
  int P = idx >> 14;
  if (P >= 10) return;
  int b = P / 5, l = P % 5;
  int n = (int)((const u32*)(ws + NV_OFF))[P];
  int W = (n + 63) >> 6;
  if (i >= n || w >= W) return;
  float M = __uint_as_float(((const u32*)(ws + MAXC_OFF))[b]);
  float maxc = __fadd_rn(M, 1.0f);
  float off = __fmul_rn((float)l, maxc);
  const float4* lbox = (const float4*)(ws + LBOX_OFF) + (size_t)P * 1024;
  float4 bi = lbox[i];
  bi.x = __fadd_rn(bi.x, off); bi.y = __fadd_rn(bi.y, off);
  bi.z = __fadd_rn(bi.z, off); bi.w = __fadd_rn(bi.w, off);
  float ai = __fmul_rn(__fsub_rn(bi.z, bi.x), __fsub_rn(bi.w, bi.y));
  u64 word = 0;
  int j0 = w << 6;
  int jn = min(64, n - j0);
  for (int jj = 0; jj < jn; ++jj) {
    float4 bj = lbox[j0 + jj];
    bj.x = __fadd_rn(bj.x, off); bj.y = __fadd_rn(bj.y, off);
    bj.z = __fadd_rn(bj.z, off); bj.w = __fadd_rn(bj.w, off);
    float xx1 = fmaxf(bi.x, bj.x);
    float yy1 = fmaxf(bi.y, bj.y);
    float xx2 = fminf(bi.z, bj.z);
    float yy2 = fminf(bi.w, bj.w);
    float iw = fmaxf(__fsub_rn(xx2, xx1), 0.0f);
    float ih = fmaxf(__fsub_rn(yy2, yy1), 0.0f);
    float inter = __fmul_rn(iw, ih);
    float aj = __fmul_rn(__fsub_rn(bj.z, bj.x), __fsub_rn(bj.w, bj.y));
    float den = __fadd_rn(__fsub_rn(__fadd_rn(ai, aj), inter), 1e-9f);
    float iou = __fdiv_rn(inter, den);
    if (iou > 0.7f) word |= (1ull << jj);
  }
  if (i >= j0 && i < j0 + 64) word &= ~(1ull << (i - j0));   // zero diagonal
  ((u64*)(ws + MASK_OFF))[(size_t)P * 16000 + (size_t)i * W + w] = word;
  if (word)
    atomicOr((u64*)(ws + CHUNKANY_OFF) + (size_t)P * 16 + (i >> 6), 1ull << (i & 63));
}

// ---------- 6) NMS scan (5 waves = 5 levels) + rank bitmap + emit ----------
__global__ __launch_bounds__(320)
void k_scanfin(float* __restrict__ out, char* __restrict__ ws) {
  __shared__ u64 keeps[5][16];
  __shared__ u32 kb[160];
  int tid = threadIdx.x, w = tid >> 6, lane = tid & 63;
  int b = blockIdx.x;
  for (int i = tid; i < 160; i += 320) kb[i] = 0u;
  for (int i = tid; i < 4000; i += 320) out[(size_t)b * 4000 + i] = 0.0f;
  for (int i = tid; i < 1000; i += 320) out[8000 + (size_t)b * 1000 + i] = 0.0f;
  int P = b * 5 + w;
  int n = (int)((const u32*)(ws + NV_OFF))[P];
  int W = (n + 63) >> 6;
  const u64* maskg = (const u64*)(ws + MASK_OFF) + (size_t)P * 16000;
  const u64* chunkany = (const u64*)(ws + CHUNKANY_OFF) + (size_t)P * 16;
  u64 removed = 0, keepw = 0;
  for (int c = 0; c < W; ++c) {
    int rb = c << 6;
    int rows = min(64, n - rb);
    u64 rowsmask = (rows == 64) ? ~0ull : ((1ull << rows) - 1ull);
    u64 curw = __shfl(removed, c);
    u64 cand = ~curw & rowsmask;
    u64 anyrows = chunkany[c] & cand;
    u64 keptbits;
    if (anyrows == 0ull) {
      keptbits = cand;
    } else {
      u64 diag = (lane < rows) ? maskg[(size_t)(rb + lane) * W + c] : 0ull;
      u64 diagnz = __ballot(diag != 0ull);
      if ((diagnz & cand) == 0ull) {
        keptbits = cand;
      } else {
        u64 remw = curw | ~rowsmask;
        u64 kept = 0;
        for (int r = 0; r < rows; ++r) {
          u64 dr = __shfl(diag, r);
          bool k = ((remw >> r) & 1ull) == 0ull;
          u64 sel = k ? ~0ull : 0ull;
          remw |= dr & sel;
          kept |= ((u64)(k ? 1 : 0)) << r;
        }
        keptbits = kept;
      }
      u64 todo = keptbits & chunkany[c];
      while (todo) {
        int r = __builtin_ctzll(todo);
        todo &= todo - 1;
        u64 rowv = (lane < W) ? maskg[(size_t)(rb + r) * W + lane] : 0ull;
        removed |= rowv;
      }
    }
    if (lane == c) keepw |= keptbits;
  }
  if (lane < 16) keeps[w][lane] = keepw;
  __syncthreads();
  for (int idx = tid; idx < 5120; idx += 320) {
    int p = idx >> 10, i = idx & 1023;
    int Pp = b * 5 + p;
    if (i < (int)((const u32*)(ws + NV_OFF))[Pp]) {
      if ((keeps[p][i >> 6] >> (i & 63)) & 1ull) {
        u32 r = ((const u32*)(ws + RANK_OFF))[(size_t)Pp * 1024 + i];
        atomicOr(&kb[r >> 5], 1u << (r & 31));
      }
    }
  }
  __syncthreads();
  if (tid < 64) {
    int base = 0;
    for (int wd = 0; wd < 72; ++wd) {
      u64 word = ((u64)kb[2 * wd + 1] << 32) | (u64)kb[2 * wd];
      bool mine = (word >> lane) & 1ull;
      int slot = base + __popcll(word & ((1ull << lane) - 1ull));
      if (mine && slot < KTOP) {
        int r = wd * 64 + lane;
        u32 g = ((const u32*)(ws + GL_OFF))[(size_t)b * 4608 + r];
        int l = g >> 16, i = g & 0xFFFF;
        int Pp = b * 5 + l;
        float4 bx = ((const float4*)(ws + LBOX_OFF))[(size_t)Pp * 1024 + i];
        float s = ((const float*)(ws + LSC_OFF))[(size_t)Pp * 1024 + i];
        float* ob = out + ((size_t)b * KTOP + slot) * 4;
        ob[0] = bx.x; ob[1] = bx.y; ob[2] = bx.z; ob[3] = bx.w;
        out[8000 + (size_t)b * KTOP + slot] = s;
      }
      base += __popcll(word);
    }
  }
}

extern "C" void kernel_launch(void* const* d_in, const int* in_sizes, int n_in,
                              void* d_out, int out_size, void* d_ws, size_t ws_size,
                              hipStream_t stream) {
  const float* pred = (const float*)d_in[0];
  const float* obj  = (const float*)d_in[1];
  const float* anch = (const float*)d_in[2];
  const float* vs   = (const float*)d_in[3];
  float* out = (float*)d_out;
  char* ws = (char*)d_ws;
  (void)in_sizes; (void)n_in; (void)out_size; (void)ws_size;

  int gZ = (int)((ZERO_END / 4 + 255) / 256);
  k_zero      <<<gZ,        256, 0, stream>>>(ws);
  k_hist12    <<<BS * NBH,  256, 0, stream>>>(obj, ws);
  k_compactsel<<<BS * NBH,  256, 0, stream>>>(obj, ws);
  k_sortdec   <<<10,        256, 0, stream>>>(pred, obj, anch, vs, ws);
  k_maskrank  <<<640,       256, 0, stream>>>(ws);
  k_scanfin   <<<2,         320, 0, stream>>>(out, ws);
}

// Round 7
// 194.602 us; speedup vs baseline: 2.7635x; 1.1505x over previous
//
#include <hip/hip_runtime.h>

typedef unsigned int u32;
typedef unsigned long long u64;

#define A_TOT    159882
#define BS       2
#define KTOP     1000
#define CAND_CAP 4096
#define HB       4096        // 12-bit histogram buckets per segment
#define ABLK     4096        // anchors per hist/compact block
#define NBH      40          // blocks per image (40*4096 >= A_TOT)
#define EPT      16          // ABLK/256

// ---- workspace layout (bytes) ----
static const size_t HIST12_OFF   = 0;         // u32[8*4096] = 128 KB (L2-resident)
static const size_t CUT_OFF      = 131072;    // u32[8]
static const size_t CCNT_OFF     = 131104;    // u32[8]
static const size_t MAXC_OFF     = 131136;    // u32[2]
static const size_t NV_OFF       = 131144;    // u32[10]
static const size_t CHUNKANY_OFF = 131200;    // u64[10*16]
static const size_t ZERO_END     = 132480;    // k_zero covers [0, ZERO_END)
static const size_t CAND_OFF     = 132480;    // u64[8*4096]
static const size_t LKEY2_OFF    = 394624;    // u64[10*1024]
static const size_t LBOX_OFF     = 476544;    // float4[10*1024]
static const size_t LSC_OFF      = 640384;    // float[10*1024]
static const size_t RANK_OFF     = 681344;    // u32[10*1024]
static const size_t MASK_OFF     = 759168;    // u64[10*16000]
// total ~2.04 MB

__device__ __forceinline__ int level_of(int a) {
  if (a < 120000) return 0;
  if (a < 150000) return 1;
  if (a < 157500) return 2;
  if (a < 159375) return 3;
  return 4;
}

// monotone decreasing transform: smaller d == larger score; d(-inf)=0xFF800000
__device__ __forceinline__ u32 dkey(float s) {
  u32 b = __float_as_uint(s);
  return (b & 0x80000000u) ? b : (~b & 0x7FFFFFFFu);
}

// bit-exact replica of reference decode + clip + min-size check
__device__ __forceinline__ void decode_clip(const float* __restrict__ pred,
                                            const float* __restrict__ anch,
                                            const float* __restrict__ vs,
                                            int b, int a,
                                            float& x1c, float& y1c, float& x2c, float& y2c,
                                            bool& valid) {
  const float* pp = pred + ((size_t)b * A_TOT + (size_t)a) * 4;
  const float* aa = anch + (size_t)a * 4;
  float ax1 = aa[0], ay1 = aa[1], ax2 = aa[2], ay2 = aa[3];
  float px = pp[0], py = pp[1], pw = pp[2], ph = pp[3];
  float aw  = __fsub_rn(ax2, ax1);
  float ah  = __fsub_rn(ay2, ay1);
  float acx = __fadd_rn(ax1, __fmul_rn(0.5f, aw));
  float acy = __fadd_rn(ay1, __fmul_rn(0.5f, ah));
  float cx  = __fadd_rn(acx, __fmul_rn(px, aw));
  float cy  = __fadd_rn(acy, __fmul_rn(py, ah));
  float w   = __fmul_rn(expf(pw), aw);
  float h   = __fmul_rn(expf(ph), ah);
  float x1  = __fsub_rn(cx, __fmul_rn(0.5f, w));
  float y1  = __fsub_rn(cy, __fmul_rn(0.5f, h));
  float x2  = __fadd_rn(x1, w);
  float y2  = __fadd_rn(y1, h);
  float Wv = vs[b * 2 + 0], Hv = vs[b * 2 + 1];
  x1c = fminf(fmaxf(x1, 0.0f), Wv);
  y1c = fminf(fmaxf(y1, 0.0f), Hv);
  x2c = fminf(fmaxf(x2, 0.0f), Wv);
  y2c = fminf(fmaxf(y2, 0.0f), Hv);
  valid = (__fsub_rn(x2c, x1c) > 0.001f) && (__fsub_rn(y2c, y1c) > 0.001f);
}

__device__ __forceinline__ void bitonic_u64(u64* arr, int N, int t, int nt) {
  for (int k = 2; k <= N; k <<= 1) {
    for (int j = k >> 1; j > 0; j >>= 1) {
      __syncthreads();
      for (int i = t; i < N; i += nt) {
        int ixj = i ^ j;
        if (ixj > i) {
          u64 x = arr[i], y = arr[ixj];
          bool up = ((i & k) == 0);
          if (up ? (x > y) : (x < y)) { arr[i] = y; arr[ixj] = x; }
        }
      }
    }
  }
  __syncthreads();
}

__device__ __forceinline__ int lbound(const u64* __restrict__ arr, int n, u64 key) {
  int lo = 0, hi = n;
  while (lo < hi) { int mid = (lo + hi) >> 1; if (arr[mid] < key) lo = mid + 1; else hi = mid; }
  return lo;
}

// ---------- 1) zero control + histogram region ----------
__global__ void k_zero(char* __restrict__ ws) {
  size_t i = (size_t)blockIdx.x * blockDim.x + threadIdx.x;
  if (i * 4 < ZERO_END) ((u32*)ws)[i] = 0u;
}

// ---------- 2) 12-bit histogram, LDS-privatized (<=2 segments/block) ----------
__global__ void k_hist12(const float* __restrict__ obj, char* __restrict__ ws) {
  __shared__ u32 h[2 * HB];   // 32 KB
  int tid = threadIdx.x;
  int b = blockIdx.x / NBH, loc = blockIdx.x % NBH;
  int start = loc * ABLK;
  int l0 = level_of(start);
  if (l0 >= 4) return;
  for (int i = tid; i < 2 * HB; i += 256) h[i] = 0u;
  __syncthreads();
  for (int it = 0; it < EPT; ++it) {
    int a = start + it * 256 + tid;
    if (a < A_TOT) {
      int l = level_of(a);
      if (l < 4) {
        u32 d = dkey(obj[(size_t)b * A_TOT + a]);
        atomicAdd(&h[(u32)(l - l0) * HB + (d >> 20)], 1u);
      }
    }
  }
  __syncthreads();
  int lend = level_of(min(start + ABLK - 1, A_TOT - 1));
  int nseg = ((l0 + 1 <= lend) && (l0 + 1 < 4)) ? 2 : 1;
  for (int s = 0; s < nseg; ++s) {
    u32* gh = (u32*)(ws + HIST12_OFF) + (size_t)(b * 4 + l0 + s) * HB;
    for (int i = tid; i < HB; i += 256) {
      u32 v = h[s * HB + i];
      if (v) atomicAdd(&gh[i], v);
    }
  }
}

// ---------- 3) inline cutoff + block-aggregated candidate append ----------
__global__ void k_compactsel(const float* __restrict__ obj, char* __restrict__ ws) {
  __shared__ u32 scan[256];
  __shared__ u32 cutv[2];
  __shared__ u32 lcnt[2], gbase[2];
  int tid = threadIdx.x, lane = tid & 63;
  int b = blockIdx.x / NBH, loc = blockIdx.x % NBH;
  int start = loc * ABLK;
  int l0 = level_of(start);
  if (l0 >= 4) return;
  int lend = level_of(min(start + ABLK - 1, A_TOT - 1));
  int nseg = ((l0 + 1 <= lend) && (l0 + 1 < 4)) ? 2 : 1;
  if (tid < 2) lcnt[tid] = 0;
  // recompute segment cutoffs from L2-resident hist (idempotent across blocks)
  for (int s = 0; s < nseg; ++s) {
    int seg = b * 4 + l0 + s;
    const u32* gh = (const u32*)(ws + HIST12_OFF) + (size_t)seg * HB;
    u32 vals[16]; u32 acc = 0;
    for (int q = 0; q < 16; ++q) { vals[q] = gh[tid * 16 + q]; acc += vals[q]; }
    __syncthreads();
    scan[tid] = acc; __syncthreads();
    for (int d = 1; d < 256; d <<= 1) {
      u32 x = (tid >= d) ? scan[tid - d] : 0u; __syncthreads();
      scan[tid] += x; __syncthreads();
    }
    u32 incl = scan[tid], prev = incl - acc;
    if (prev < KTOP && incl >= KTOP) {
      u32 run = prev; int cb = HB - 1;
      for (int q = 0; q < 16; ++q) { run += vals[q]; if (run >= KTOP) { cb = tid * 16 + q; break; } }
      cutv[s] = (u32)cb;
      ((u32*)(ws + CUT_OFF))[seg] = (u32)cb;
    }
  }
  __syncthreads();
  u32 dv[EPT], slotv[EPT], passm = 0, sim = 0;
  for (int it = 0; it < EPT; ++it) {
    int a = start + it * 256 + tid;
    bool pass = false; u32 si = 0, d = 0;
    if (a < A_TOT) {
      int l = level_of(a);
      if (l < 4) {
        si = (u32)(l - l0);
        d = dkey(obj[(size_t)b * A_TOT + a]);
        pass = (d >> 20) <= cutv[si];
      }
    }
    dv[it] = d;
    u64 mp = __ballot(pass);
    u64 m1 = __ballot(pass && si == 1);
    u64 m0 = mp & ~m1;
    u32 slot = 0;
    if (m0) {
      int ld = __builtin_ctzll(m0);
      u32 wb = 0;
      if (lane == ld) wb = atomicAdd(&lcnt[0], (u32)__popcll(m0));
      wb = __shfl(wb, ld);
      if (pass && si == 0) slot = wb + (u32)__popcll(m0 & ((1ull << lane) - 1ull));
    }
    if (m1) {
      int ld = __builtin_ctzll(m1);
      u32 wb = 0;
      if (lane == ld) wb = atomicAdd(&lcnt[1], (u32)__popcll(m1));
      wb = __shfl(wb, ld);
      if (pass && si == 1) slot = wb + (u32)__popcll(m1 & ((1ull << lane) - 1ull));
    }
    slotv[it] = slot;
    if (pass) { passm |= 1u << it; if (si) sim |= 1u << it; }
  }
  __syncthreads();
  if (tid < 2)
    gbase[tid] = lcnt[tid] ? atomicAdd((u32*)(ws + CCNT_OFF) + (b * 4 + l0 + tid), lcnt[tid]) : 0u;
  __syncthreads();
  for (int it = 0; it < EPT; ++it) {
    if ((passm >> it) & 1u) {
      int a = start + it * 256 + tid;
      u32 si = (sim >> it) & 1u;
      int seg = b * 4 + l0 + (int)si;
      u32 gslot = gbase[si] + slotv[it];
      if (gslot < CAND_CAP)
        ((u64*)(ws + CAND_OFF))[(size_t)seg * CAND_CAP + gslot] =
            ((u64)dv[it] << 32) | (u32)a;
    }
  }
}

// ---------- 4) per-(image,level): 20-bit refine + sort + decode + compaction ----------
__global__ void k_sortdec(const float* __restrict__ pred, const float* __restrict__ obj,
                          const float* __restrict__ anch, const float* __restrict__ vs,
                          char* __restrict__ ws) {
  __shared__ u64 arr[CAND_CAP];       // 32 KB
  __shared__ float4 dboxL[1024];      // 16 KB
  __shared__ float dscL[1024];        // 4 KB
  __shared__ u64 vmask[16];
  __shared__ u32 h8[256];
  __shared__ u32 auxv[4];             // [0]=cnt_below [1]=append pos [2]=cut20 [3]=sel_total
  int tid = threadIdx.x, lane = tid & 63, wv = tid >> 6;
  int P = blockIdx.x, b = P / 5, l = P % 5;
  int n;
  if (l == 4) {
    n = 507;
    for (int i = tid; i < 512; i += 256) {
      u64 v = ~0ull;
      if (i < 507) { int a = 159375 + i; v = ((u64)dkey(obj[(size_t)b * A_TOT + a]) << 32) | (u32)a; }
      arr[i] = v;
    }
    bitonic_u64(arr, 512, tid, 256);
  } else {
    n = KTOP;
    int seg = b * 4 + l;
    u32 cnt = min(((const u32*)(ws + CCNT_OFF))[seg], (u32)CAND_CAP);
    u32 cut12 = ((const u32*)(ws + CUT_OFF))[seg];
    const u64* cand = (const u64*)(ws + CAND_OFF) + (size_t)seg * CAND_CAP;
    int N;
    if (cnt <= 2048) {
      u64 ev[8];
      for (int j = 0; j < 8; ++j) { int idx = j * 256 + tid; ev[j] = (idx < (int)cnt) ? cand[idx] : ~0ull; }
      h8[tid] = 0;
      if (tid < 4) auxv[tid] = 0;
      __syncthreads();
      u32 myb = 0;
      for (int j = 0; j < 8; ++j) {
        int idx = j * 256 + tid;
        if (idx < (int)cnt) {
          u32 b12 = (u32)(ev[j] >> 52);
          if (b12 < cut12) myb++;
          else atomicAdd(&h8[(u32)(ev[j] >> 44) & 0xFFu], 1u);
        }
      }
      for (int off = 32; off; off >>= 1) myb += __shfl_xor(myb, off);
      if (lane == 0) atomicAdd(&auxv[0], myb);
      __syncthreads();
      u32 cntb = auxv[0];
      u32 hv = h8[tid];
      __syncthreads();
      for (int d = 1; d < 256; d <<= 1) {
        u32 x = (tid >= d) ? h8[tid - d] : 0u; __syncthreads();
        h8[tid] += x; __syncthreads();
      }
      u32 incl = h8[tid], excl = incl - hv;
      if (cntb + incl >= KTOP && cntb + excl < KTOP) { auxv[2] = (u32)tid; auxv[3] = cntb + incl; }
      __syncthreads();
      u32 cut20 = auxv[2]; u32 selt = auxv[3];
      for (int i = tid; i < 2048; i += 256) arr[i] = ~0ull;
      __syncthreads();
      for (int j = 0; j < 8; ++j) {
        int idx = j * 256 + tid;
        if (idx < (int)cnt) {
          u32 b12 = (u32)(ev[j] >> 52);
          bool sel = (b12 < cut12) || (((u32)(ev[j] >> 44) & 0xFFu) <= cut20);
          if (sel) { u32 p = atomicAdd(&auxv[1], 1u); arr[p] = ev[j]; }
        }
      }
      __syncthreads();
      N = 1024; while (N < (int)selt) N <<= 1;
    } else {
      for (int i = tid; i < CAND_CAP; i += 256) arr[i] = (i < (int)cnt) ? cand[i] : ~0ull;
      N = 1024; while (N < (int)cnt) N <<= 1;
    }
    bitonic_u64(arr, N, tid, 256);
  }
  // decode + per-image max coord
  float m = 0.0f;
  for (int k = 0; k < 4; ++k) {
    int j = k * 256 + tid;
    bool vb = false;
    if (j < n) {
      u64 key = arr[j];
      int a = (int)(u32)key;
      float x1, y1, x2, y2; bool valid;
      decode_clip(pred, anch, vs, b, a, x1, y1, x2, y2, valid);
      m = fmaxf(m, fmaxf(fmaxf(x1, y1), fmaxf(x2, y2)));
      dboxL[j] = make_float4(x1, y1, x2, y2);
      dscL[j] = obj[(size_t)b * A_TOT + a];
      vb = valid;
    }
    u64 bal = __ballot(vb);
    if (lane == 0) vmask[k * 4 + wv] = bal;
  }
  for (int off = 32; off; off >>= 1) m = fmaxf(m, __shfl_xor(m, off));
  if (lane == 0) atomicMax((u32*)(ws + MAXC_OFF) + b, __float_as_uint(m));
  __syncthreads();
  // stable valid-compaction (wave 0)
  if (tid < 64) {
    int base = 0;
    for (int j0 = 0; j0 < n; j0 += 64) {
      int j = j0 + lane;
      bool v = (j < n) && ((vmask[j0 >> 6] >> lane) & 1ull);
      u64 mm = __ballot(v);
      int r = base + __popcll(mm & ((1ull << lane) - 1ull));
      if (v) {
        ((u64*)(ws + LKEY2_OFF))[(size_t)P * 1024 + r] = arr[j];
        ((float4*)(ws + LBOX_OFF))[(size_t)P * 1024 + r] = dboxL[j];
        ((float*)(ws + LSC_OFF))[(size_t)P * 1024 + r] = dscL[j];
      }
      base += __popcll(mm);
    }
    if (lane == 0) ((u32*)(ws + NV_OFF))[P] = (u32)base;
  }
}

// ---------- 5) rank (blocks 0-9) + suppression bitmask (all blocks) ----------
__global__ void k_maskrank(char* __restrict__ ws) {
  int tid = threadIdx.x, bid = blockIdx.x;
  if (bid < 10) {
    int P = bid, b = P / 5, l = P % 5;
    int nv = (int)((const u32*)(ws + NV_OFF))[P];
    const u64* lkey = (const u64*)(ws + LKEY2_OFF);
    const u32* nvp = (const u32*)(ws + NV_OFF);
    for (int i = tid; i < nv; i += 256) {
      u64 key = lkey[(size_t)P * 1024 + i];
      int r = i;
      for (int l2 = 0; l2 < 5; ++l2) {
        if (l2 == l) continue;
        int P2 = b * 5 + l2;
        r += lbound(lkey + (size_t)P2 * 1024, (int)nvp[P2], key);
      }
      ((u32*)(ws + RANK_OFF))[(size_t)P * 1024 + i] = (u32)r;
    }
  }
  int idx = bid * 256 + tid;       // 640*256 = 163840 items
  int w = idx & 15;
  int i = (idx >> 4) & 1023;
  int P = idx >> 14;
  if (P >= 10) return;
  int b = P / 5, l = P % 5;
  int n = (int)((const u32*)(ws + NV_OFF))[P];
  int W = (n + 63) >> 6;
  if (i >= n || w >= W) return;
  float M = __uint_as_float(((const u32*)(ws + MAXC_OFF))[b]);
  float maxc = __fadd_rn(M, 1.0f);
  float off = __fmul_rn((float)l, maxc);
  const float4* lbox = (const float4*)(ws + LBOX_OFF) + (size_t)P * 1024;
  float4 bi = lbox[i];
  bi.x = __fadd_rn(bi.x, off); bi.y = __fadd_rn(bi.y, off);
  bi.z = __fadd_rn(bi.z, off); bi.w = __fadd_rn(bi.w, off);
  float ai = __fmul_rn(__fsub_rn(bi.z, bi.x), __fsub_rn(bi.w, bi.y));
  u64 word = 0;
  int j0 = w << 6;
  int jn = min(64, n - j0);
  for (int jj = 0; jj < jn; ++jj) {
    float4 bj = lbox[j0 + jj];
    bj.x = __fadd_rn(bj.x, off); bj.y = __fadd_rn(bj.y, off);
    bj.z = __fadd_rn(bj.z, off); bj.w = __fadd_rn(bj.w, off);
    float xx1 = fmaxf(bi.x, bj.x);
    float yy1 = fmaxf(bi.y, bj.y);
    float xx2 = fminf(bi.z, bj.z);
    float yy2 = fminf(bi.w, bj.w);
    float iw = fmaxf(__fsub_rn(xx2, xx1), 0.0f);
    float ih = fmaxf(__fsub_rn(yy2, yy1), 0.0f);
    float inter = __fmul_rn(iw, ih);
    float aj = __fmul_rn(__fsub_rn(bj.z, bj.x), __fsub_rn(bj.w, bj.y));
    float den = __fadd_rn(__fsub_rn(__fadd_rn(ai, aj), inter), 1e-9f);
    float iou = __fdiv_rn(inter, den);
    if (iou > 0.7f) word |= (1ull << jj);
  }
  if (i >= j0 && i < j0 + 64) word &= ~(1ull << (i - j0));   // zero diagonal
  ((u64*)(ws + MASK_OFF))[(size_t)P * 16000 + (size_t)i * W + w] = word;
  if (word)
    atomicOr((u64*)(ws + CHUNKANY_OFF) + (size_t)P * 16 + (i >> 6), 1ull << (i & 63));
}

// ---------- 6) NMS scan (5 waves = 5 levels), latency-optimized + parallel emit ----------
__global__ __launch_bounds__(320)
void k_scanfin(float* __restrict__ out, char* __restrict__ ws) {
  __shared__ u64 keeps[5][16];
  __shared__ u64 kb[80];
  __shared__ u32 sb[128];
  __shared__ u32 pfx[80];
  __shared__ u32 nvs[5];
  int tid = threadIdx.x, w = tid >> 6, lane = tid & 63;
  int b = blockIdx.x;
  for (int i = tid; i < 80; i += 320) kb[i] = 0ull;
  for (int i = tid; i < 4000; i += 320) out[(size_t)b * 4000 + i] = 0.0f;
  for (int i = tid; i < 1000; i += 320) out[8000 + (size_t)b * 1000 + i] = 0.0f;
  if (tid < 5) nvs[tid] = ((const u32*)(ws + NV_OFF))[b * 5 + tid];

  int P = b * 5 + w;
  int n = (int)((const u32*)(ws + NV_OFF))[P];
  int W = (n + 63) >> 6;
  const u64* maskg = (const u64*)(ws + MASK_OFF) + (size_t)P * 16000;
  // prefetch chunkany (1 load) and all diag words (burst of <=16 independent loads)
  u64 ca = (lane < 16) ? ((const u64*)(ws + CHUNKANY_OFF))[(size_t)P * 16 + lane] : 0ull;
  u64 dpre[16];
#pragma unroll
  for (int c = 0; c < 16; ++c) {
    int row = (c << 6) + lane;
    dpre[c] = (c < W && row < n) ? maskg[(size_t)row * W + c] : 0ull;
  }
  u64 removed = 0ull, keepw = 0ull;
#pragma unroll
  for (int c = 0; c < 16; ++c) {
    if (c >= W) break;
    int rb = c << 6;
    int rows = min(64, n - rb);
    u64 rowsmask = (rows == 64) ? ~0ull : ((1ull << rows) - 1ull);
    u64 curw = __shfl(removed, c);
    u64 cand = ~curw & rowsmask;
    u64 ca_c = __shfl(ca, c);
    u64 keptbits;
    u64 anyrows = ca_c & cand;
    if (anyrows == 0ull) {
      keptbits = cand;
    } else {
      u64 diag = dpre[c];
      u64 diagnz = __ballot(diag != 0ull) & cand;
      if (diagnz == 0ull) {
        keptbits = cand;
      } else {
        // sparse serial chain: only rows with nonzero diag need sequencing
        u64 remw = curw | ~rowsmask;
        u64 kept = 0ull;
        int pos = 0;
        u64 work = diagnz;
        while (work) {
          int s = __builtin_ctzll(work); work &= work - 1;
          u64 range = (1ull << s) - (1ull << pos);   // bits pos..s-1
          kept |= ~remw & range;                      // zero-diag rows: kept iff alive
          bool k = ((remw >> s) & 1ull) == 0ull;      // uniform across lanes
          u64 dr = __shfl(diag, s);
          if (k) { kept |= 1ull << s; remw |= dr; }
          pos = s + 1;
        }
        u64 tail = (pos >= 64) ? 0ull : (~0ull << pos);
        kept |= ~remw & tail & rowsmask;
        keptbits = kept;
      }
      // cross-chunk OR of kept rows with any bits, batched x4 (independent loads)
      u64 todo = keptbits & ca_c;
      while (todo) {
        int r0 = __builtin_ctzll(todo); todo &= todo - 1;
        int r1 = -1, r2 = -1, r3 = -1;
        if (todo) { r1 = __builtin_ctzll(todo); todo &= todo - 1; }
        if (todo) { r2 = __builtin_ctzll(todo); todo &= todo - 1; }
        if (todo) { r3 = __builtin_ctzll(todo); todo &= todo - 1; }
        u64 v0 = 0, v1 = 0, v2 = 0, v3 = 0;
        if (lane < W) {
          v0 = maskg[(size_t)(rb + r0) * W + lane];
          if (r1 >= 0) v1 = maskg[(size_t)(rb + r1) * W + lane];
          if (r2 >= 0) v2 = maskg[(size_t)(rb + r2) * W + lane];
          if (r3 >= 0) v3 = maskg[(size_t)(rb + r3) * W + lane];
        }
        removed |= v0 | v1 | v2 | v3;
      }
    }
    if (lane == c) keepw |= keptbits;
  }
  if (lane < 16) keeps[w][lane] = keepw;
  __syncthreads();

  // build rank bitmap (parallel)
  const u32* rank = (const u32*)(ws + RANK_OFF);
  for (int idx = tid; idx < 5120; idx += 320) {
    int p = idx >> 10, i = idx & 1023;
    if (i < (int)nvs[p] && ((keeps[p][i >> 6] >> (i & 63)) & 1ull)) {
      u32 r = rank[(size_t)(b * 5 + p) * 1024 + i];
      atomicOr(&kb[r >> 6], 1ull << (r & 63));
    }
  }
  __syncthreads();
  // exclusive prefix of popcounts over 80 words (Hillis-Steele, 128-wide)
  if (tid < 128) sb[tid] = (tid < 80) ? (u32)__popcll(kb[tid]) : 0u;
  __syncthreads();
  for (int d = 1; d < 128; d <<= 1) {
    u32 x = (tid < 128 && tid >= d) ? sb[tid - d] : 0u;
    __syncthreads();
    if (tid < 128) sb[tid] += x;
    __syncthreads();
  }
  if (tid < 80) pfx[tid] = sb[tid] - (u32)__popcll(kb[tid]);
  __syncthreads();
  // parallel emit
  for (int idx = tid; idx < 5120; idx += 320) {
    int p = idx >> 10, i = idx & 1023;
    if (i < (int)nvs[p] && ((keeps[p][i >> 6] >> (i & 63)) & 1ull)) {
      int Pp = b * 5 + p;
      u32 r = rank[(size_t)Pp * 1024 + i];
      u64 word = kb[r >> 6];
      int slot = (int)pfx[r >> 6] + __popcll(word & ((1ull << (r & 63)) - 1ull));
      if (slot < KTOP) {
        float4 bx = ((const float4*)(ws + LBOX_OFF))[(size_t)Pp * 1024 + i];
        float s = ((const float*)(ws + LSC_OFF))[(size_t)Pp * 1024 + i];
        float* ob = out + ((size_t)b * KTOP + slot) * 4;
        ob[0] = bx.x; ob[1] = bx.y; ob[2] = bx.z; ob[3] = bx.w;
        out[8000 + (size_t)b * KTOP + slot] = s;
      }
    }
  }
}

extern "C" void kernel_launch(void* const* d_in, const int* in_sizes, int n_in,
                              void* d_out, int out_size, void* d_ws, size_t ws_size,
                              hipStream_t stream) {
  const float* pred = (const float*)d_in[0];
  const float* obj  = (const float*)d_in[1];
  const float* anch = (const float*)d_in[2];
  const float* vs   = (const float*)d_in[3];
  float* out = (float*)d_out;
  char* ws = (char*)d_ws;
  (void)in_sizes; (void)n_in; (void)out_size; (void)ws_size;

  int gZ = (int)((ZERO_END / 4 + 255) / 256);
  k_zero      <<<gZ,        256, 0, stream>>>(ws);
  k_hist12    <<<BS * NBH,  256, 0, stream>>>(obj, ws);
  k_compactsel<<<BS * NBH,  256, 0, stream>>>(obj, ws);
  k_sortdec   <<<10,        256, 0, stream>>>(pred, obj, anch, vs, ws);
  k_maskrank  <<<640,       256, 0, stream>>>(ws);
  k_scanfin   <<<2,         320, 0, stream>>>(out, ws);
}

// Round 8
// 193.763 us; speedup vs baseline: 2.7754x; 1.0043x over previous
//
#include <hip/hip_runtime.h>

typedef unsigned int u32;
typedef unsigned long long u64;

#define A_TOT    159882
#define BS       2
#define KTOP     1000
#define CAND_CAP 4096
#define HB       4096        // 12-bit histogram buckets per segment
#define ABLK     4096        // anchors per hist/compact block
#define NBH      40          // blocks per image (40*4096 >= A_TOT)
#define EPT      16          // ABLK/256

// ---- workspace layout (bytes) ----
static const size_t HIST12_OFF   = 0;         // u32[8*4096] = 128 KB (L2-resident)
static const size_t CUT_OFF      = 131072;    // u32[8]
static const size_t CCNT_OFF     = 131104;    // u32[8]
static const size_t MAXC_OFF     = 131136;    // u32[2]
static const size_t NV_OFF       = 131144;    // u32[10]
static const size_t CHUNKANY_OFF = 131200;    // u64[10*16]
static const size_t ZERO_END     = 132480;    // k_zero covers [0, ZERO_END)
static const size_t CAND_OFF     = 132480;    // u64[8*4096]
static const size_t LKEY2_OFF    = 394624;    // u64[10*1024]
static const size_t LBOX_OFF     = 476544;    // float4[10*1024]
static const size_t LSC_OFF      = 640384;    // float[10*1024]
static const size_t RANK_OFF     = 681344;    // u32[10*1024]
static const size_t MASK_OFF     = 759168;    // u64[10*16000]
// total ~2.04 MB

__device__ __forceinline__ int level_of(int a) {
  if (a < 120000) return 0;
  if (a < 150000) return 1;
  if (a < 157500) return 2;
  if (a < 159375) return 3;
  return 4;
}

// monotone decreasing transform: smaller d == larger score; d(-inf)=0xFF800000
__device__ __forceinline__ u32 dkey(float s) {
  u32 b = __float_as_uint(s);
  return (b & 0x80000000u) ? b : (~b & 0x7FFFFFFFu);
}

// bit-exact replica of reference decode + clip + min-size check
__device__ __forceinline__ void decode_clip(const float* __restrict__ pred,
                                            const float* __restrict__ anch,
                                            const float* __restrict__ vs,
                                            int b, int a,
                                            float& x1c, float& y1c, float& x2c, float& y2c,
                                            bool& valid) {
  const float* pp = pred + ((size_t)b * A_TOT + (size_t)a) * 4;
  const float* aa = anch + (size_t)a * 4;
  float ax1 = aa[0], ay1 = aa[1], ax2 = aa[2], ay2 = aa[3];
  float px = pp[0], py = pp[1], pw = pp[2], ph = pp[3];
  float aw  = __fsub_rn(ax2, ax1);
  float ah  = __fsub_rn(ay2, ay1);
  float acx = __fadd_rn(ax1, __fmul_rn(0.5f, aw));
  float acy = __fadd_rn(ay1, __fmul_rn(0.5f, ah));
  float cx  = __fadd_rn(acx, __fmul_rn(px, aw));
  float cy  = __fadd_rn(acy, __fmul_rn(py, ah));
  float w   = __fmul_rn(expf(pw), aw);
  float h   = __fmul_rn(expf(ph), ah);
  float x1  = __fsub_rn(cx, __fmul_rn(0.5f, w));
  float y1  = __fsub_rn(cy, __fmul_rn(0.5f, h));
  float x2  = __fadd_rn(x1, w);
  float y2  = __fadd_rn(y1, h);
  float Wv = vs[b * 2 + 0], Hv = vs[b * 2 + 1];
  x1c = fminf(fmaxf(x1, 0.0f), Wv);
  y1c = fminf(fmaxf(y1, 0.0f), Hv);
  x2c = fminf(fmaxf(x2, 0.0f), Wv);
  y2c = fminf(fmaxf(y2, 0.0f), Hv);
  valid = (__fsub_rn(x2c, x1c) > 0.001f) && (__fsub_rn(y2c, y1c) > 0.001f);
}

__device__ __forceinline__ void bitonic_u64(u64* arr, int N, int t, int nt) {
  for (int k = 2; k <= N; k <<= 1) {
    for (int j = k >> 1; j > 0; j >>= 1) {
      __syncthreads();
      for (int i = t; i < N; i += nt) {
        int ixj = i ^ j;
        if (ixj > i) {
          u64 x = arr[i], y = arr[ixj];
          bool up = ((i & k) == 0);
          if (up ? (x > y) : (x < y)) { arr[i] = y; arr[ixj] = x; }
        }
      }
    }
  }
  __syncthreads();
}

__device__ __forceinline__ u64 shfl_xor_u64(u64 x, int lanemask) {
  u32 lo = (u32)x, hi = (u32)(x >> 32);
  lo = (u32)__shfl_xor((int)lo, lanemask);
  hi = (u32)__shfl_xor((int)hi, lanemask);
  return ((u64)hi << 32) | (u64)lo;
}

// register-resident bitonic sort of 2048 u64 keys (8/thread, 256 threads).
// j<8: register compare-exchange; 8<=j<=256: wave shuffle; j>=512: LDS (3 phases).
// On exit arr[0..2047] holds the ascending-sorted keys.
__device__ __forceinline__ void regsort2048(u64 v[8], int tid, u64* arr) {
  for (int k = 2; k <= 2048; k <<= 1) {
    for (int j = k >> 1; j > 0; j >>= 1) {
      if (j >= 512) {
        __syncthreads();
#pragma unroll
        for (int e = 0; e < 8; ++e) arr[tid * 8 + e] = v[e];
        __syncthreads();
#pragma unroll
        for (int e = 0; e < 8; ++e) {
          int i = tid * 8 + e, p = i ^ j;
          u64 o = arr[p];
          bool up = ((i & k) == 0);
          bool keepmin = ((i < p) == up);
          v[e] = keepmin ? (v[e] < o ? v[e] : o) : (v[e] > o ? v[e] : o);
        }
      } else if (j >= 8) {
        int dl = j >> 3;
#pragma unroll
        for (int e = 0; e < 8; ++e) {
          int i = tid * 8 + e;
          u64 o = shfl_xor_u64(v[e], dl);
          bool up = ((i & k) == 0);
          bool keepmin = (((tid & dl) == 0) == up);
          v[e] = keepmin ? (v[e] < o ? v[e] : o) : (v[e] > o ? v[e] : o);
        }
      } else {
#pragma unroll
        for (int e = 0; e < 8; ++e) {
          int pe = e ^ j;
          if (pe > e) {
            int i = tid * 8 + e;
            bool up = ((i & k) == 0);
            u64 a = v[e], b2 = v[pe];
            bool sw = up ? (a > b2) : (a < b2);
            if (sw) { v[e] = b2; v[pe] = a; }
          }
        }
      }
    }
  }
  __syncthreads();
#pragma unroll
  for (int e = 0; e < 8; ++e) arr[tid * 8 + e] = v[e];
  __syncthreads();
}

// ---------- 1) zero control + histogram region ----------
__global__ void k_zero(char* __restrict__ ws) {
  size_t i = (size_t)blockIdx.x * blockDim.x + threadIdx.x;
  if (i * 4 < ZERO_END) ((u32*)ws)[i] = 0u;
}

// ---------- 2) 12-bit histogram, LDS-privatized (<=2 segments/block) ----------
__global__ void k_hist12(const float* __restrict__ obj, char* __restrict__ ws) {
  __shared__ u32 h[2 * HB];   // 32 KB
  int tid = threadIdx.x;
  int b = blockIdx.x / NBH, loc = blockIdx.x % NBH;
  int start = loc * ABLK;
  int l0 = level_of(start);
  if (l0 >= 4) return;
  for (int i = tid; i < 2 * HB; i += 256) h[i] = 0u;
  __syncthreads();
  for (int it = 0; it < EPT; ++it) {
    int a = start + it * 256 + tid;
    if (a < A_TOT) {
      int l = level_of(a);
      if (l < 4) {
        u32 d = dkey(obj[(size_t)b * A_TOT + a]);
        atomicAdd(&h[(u32)(l - l0) * HB + (d >> 20)], 1u);
      }
    }
  }
  __syncthreads();
  int lend = level_of(min(start + ABLK - 1, A_TOT - 1));
  int nseg = ((l0 + 1 <= lend) && (l0 + 1 < 4)) ? 2 : 1;
  for (int s = 0; s < nseg; ++s) {
    u32* gh = (u32*)(ws + HIST12_OFF) + (size_t)(b * 4 + l0 + s) * HB;
    for (int i = tid; i < HB; i += 256) {
      u32 v = h[s * HB + i];
      if (v) atomicAdd(&gh[i], v);
    }
  }
}

// ---------- 3) inline cutoff + block-aggregated candidate append ----------
__global__ void k_compactsel(const float* __restrict__ obj, char* __restrict__ ws) {
  __shared__ u32 scan[256];
  __shared__ u32 cutv[2];
  __shared__ u32 lcnt[2], gbase[2];
  int tid = threadIdx.x, lane = tid & 63;
  int b = blockIdx.x / NBH, loc = blockIdx.x % NBH;
  int start = loc * ABLK;
  int l0 = level_of(start);
  if (l0 >= 4) return;
  int lend = level_of(min(start + ABLK - 1, A_TOT - 1));
  int nseg = ((l0 + 1 <= lend) && (l0 + 1 < 4)) ? 2 : 1;
  if (tid < 2) lcnt[tid] = 0;
  // recompute segment cutoffs from L2-resident hist (idempotent across blocks)
  for (int s = 0; s < nseg; ++s) {
    int seg = b * 4 + l0 + s;
    const u32* gh = (const u32*)(ws + HIST12_OFF) + (size_t)seg * HB;
    u32 vals[16]; u32 acc = 0;
    for (int q = 0; q < 16; ++q) { vals[q] = gh[tid * 16 + q]; acc += vals[q]; }
    __syncthreads();
    scan[tid] = acc; __syncthreads();
    for (int d = 1; d < 256; d <<= 1) {
      u32 x = (tid >= d) ? scan[tid - d] : 0u; __syncthreads();
      scan[tid] += x; __syncthreads();
    }
    u32 incl = scan[tid], prev = incl - acc;
    if (prev < KTOP && incl >= KTOP) {
      u32 run = prev; int cb = HB - 1;
      for (int q = 0; q < 16; ++q) { run += vals[q]; if (run >= KTOP) { cb = tid * 16 + q; break; } }
      cutv[s] = (u32)cb;
      ((u32*)(ws + CUT_OFF))[seg] = (u32)cb;
    }
  }
  __syncthreads();
  u32 dv[EPT], slotv[EPT], passm = 0, sim = 0;
  for (int it = 0; it < EPT; ++it) {
    int a = start + it * 256 + tid;
    bool pass = false; u32 si = 0, d = 0;
    if (a < A_TOT) {
      int l = level_of(a);
      if (l < 4) {
        si = (u32)(l - l0);
        d = dkey(obj[(size_t)b * A_TOT + a]);
        pass = (d >> 20) <= cutv[si];
      }
    }
    dv[it] = d;
    u64 mp = __ballot(pass);
    u64 m1 = __ballot(pass && si == 1);
    u64 m0 = mp & ~m1;
    u32 slot = 0;
    if (m0) {
      int ld = __builtin_ctzll(m0);
      u32 wb = 0;
      if (lane == ld) wb = atomicAdd(&lcnt[0], (u32)__popcll(m0));
      wb = __shfl(wb, ld);
      if (pass && si == 0) slot = wb + (u32)__popcll(m0 & ((1ull << lane) - 1ull));
    }
    if (m1) {
      int ld = __builtin_ctzll(m1);
      u32 wb = 0;
      if (lane == ld) wb = atomicAdd(&lcnt[1], (u32)__popcll(m1));
      wb = __shfl(wb, ld);
      if (pass && si == 1) slot = wb + (u32)__popcll(m1 & ((1ull << lane) - 1ull));
    }
    slotv[it] = slot;
    if (pass) { passm |= 1u << it; if (si) sim |= 1u << it; }
  }
  __syncthreads();
  if (tid < 2)
    gbase[tid] = lcnt[tid] ? atomicAdd((u32*)(ws + CCNT_OFF) + (b * 4 + l0 + tid), lcnt[tid]) : 0u;
  __syncthreads();
  for (int it = 0; it < EPT; ++it) {
    if ((passm >> it) & 1u) {
      int a = start + it * 256 + tid;
      u32 si = (sim >> it) & 1u;
      int seg = b * 4 + l0 + (int)si;
      u32 gslot = gbase[si] + slotv[it];
      if (gslot < CAND_CAP)
        ((u64*)(ws + CAND_OFF))[(size_t)seg * CAND_CAP + gslot] =
            ((u64)dv[it] << 32) | (u32)a;
    }
  }
}

// ---------- 4) per-(image,level): register bitonic sort + decode + compaction ----------
__global__ void k_sortdec(const float* __restrict__ pred, const float* __restrict__ obj,
                          const float* __restrict__ anch, const float* __restrict__ vs,
                          char* __restrict__ ws) {
  __shared__ u64 arr[CAND_CAP];       // 32 KB (sort exchange + sorted keys; 4096 for fallback)
  __shared__ float4 dboxL[1024];      // 16 KB
  __shared__ float dscL[1024];        // 4 KB
  __shared__ u64 vmask[16];
  int tid = threadIdx.x, lane = tid & 63, wv = tid >> 6;
  int P = blockIdx.x, b = P / 5, l = P % 5;
  int n;
  if (l == 4) {
    n = 507;
    u64 v[8];
#pragma unroll
    for (int e = 0; e < 8; ++e) {
      int idx = tid * 8 + e;
      if (idx < 507) {
        int a = 159375 + idx;
        v[e] = ((u64)dkey(obj[(size_t)b * A_TOT + a]) << 32) | (u32)a;
      } else v[e] = ~0ull;
    }
    regsort2048(v, tid, arr);
  } else {
    n = KTOP;
    int seg = b * 4 + l;
    u32 cnt = min(((const u32*)(ws + CCNT_OFF))[seg], (u32)CAND_CAP);
    const u64* cand = (const u64*)(ws + CAND_OFF) + (size_t)seg * CAND_CAP;
    if (cnt <= 2048) {
      u64 v[8];
#pragma unroll
      for (int e = 0; e < 8; ++e) {
        int idx = tid * 8 + e;
        v[e] = (idx < (int)cnt) ? cand[idx] : ~0ull;
      }
      regsort2048(v, tid, arr);
    } else {
      // safety fallback (statistically never taken: cnt ~= 1030)
      for (int i = tid; i < CAND_CAP; i += 256) arr[i] = (i < (int)cnt) ? cand[i] : ~0ull;
      int N = 2048; while (N < (int)cnt) N <<= 1;
      bitonic_u64(arr, N, tid, 256);
    }
  }
  // decode + per-image max coord
  float m = 0.0f;
  for (int k = 0; k < 4; ++k) {
    int j = k * 256 + tid;
    bool vb = false;
    if (j < n) {
      u64 key = arr[j];
      int a = (int)(u32)key;
      float x1, y1, x2, y2; bool valid;
      decode_clip(pred, anch, vs, b, a, x1, y1, x2, y2, valid);
      m = fmaxf(m, fmaxf(fmaxf(x1, y1), fmaxf(x2, y2)));
      dboxL[j] = make_float4(x1, y1, x2, y2);
      dscL[j] = obj[(size_t)b * A_TOT + a];
      vb = valid;
    }
    u64 bal = __ballot(vb);
    if (lane == 0) vmask[k * 4 + wv] = bal;
  }
  for (int off = 32; off; off >>= 1) m = fmaxf(m, __shfl_xor(m, off));
  if (lane == 0) atomicMax((u32*)(ws + MAXC_OFF) + b, __float_as_uint(m));
  __syncthreads();
  // stable valid-compaction (wave 0)
  if (tid < 64) {
    int base = 0;
    for (int j0 = 0; j0 < n; j0 += 64) {
      int j = j0 + lane;
      bool v = (j < n) && ((vmask[j0 >> 6] >> lane) & 1ull);
      u64 mm = __ballot(v);
      int r = base + __popcll(mm & ((1ull << lane) - 1ull));
      if (v) {
        ((u64*)(ws + LKEY2_OFF))[(size_t)P * 1024 + r] = arr[j];
        ((float4*)(ws + LBOX_OFF))[(size_t)P * 1024 + r] = dboxL[j];
        ((float*)(ws + LSC_OFF))[(size_t)P * 1024 + r] = dscL[j];
      }
      base += __popcll(mm);
    }
    if (lane == 0) ((u32*)(ws + NV_OFF))[P] = (u32)base;
  }
}

__device__ __forceinline__ int lbound(const u64* __restrict__ arr, int n, u64 key) {
  int lo = 0, hi = n;
  while (lo < hi) { int mid = (lo + hi) >> 1; if (arr[mid] < key) lo = mid + 1; else hi = mid; }
  return lo;
}

// ---------- 5) rank (blocks 0-9) + suppression bitmask (all blocks) ----------
__global__ void k_maskrank(char* __restrict__ ws) {
  int tid = threadIdx.x, bid = blockIdx.x;
  if (bid < 10) {
    int P = bid, b = P / 5, l = P % 5;
    int nv = (int)((const u32*)(ws + NV_OFF))[P];
    const u64* lkey = (const u64*)(ws + LKEY2_OFF);
    const u32* nvp = (const u32*)(ws + NV_OFF);
    for (int i = tid; i < nv; i += 256) {
      u64 key = lkey[(size_t)P * 1024 + i];
      int r = i;
      for (int l2 = 0; l2 < 5; ++l2) {
        if (l2 == l) continue;
        int P2 = b * 5 + l2;
        r += lbound(lkey + (size_t)P2 * 1024, (int)nvp[P2], key);
      }
      ((u32*)(ws + RANK_OFF))[(size_t)P * 1024 + i] = (u32)r;
    }
  }
  int idx = bid * 256 + tid;       // 640*256 = 163840 items
  int w = idx & 15;
  int i = (idx >> 4) & 1023;
  int P = idx >> 14;
  if (P >= 10) return;
  int b = P / 5, l = P % 5;
  int n = (int)((const u32*)(ws + NV_OFF))[P];
  int W = (n + 63) >> 6;
  if (i >= n || w >= W) return;
  float M = __uint_as_float(((const u32*)(ws + MAXC_OFF))[b]);
  float maxc = __fadd_rn(M, 1.0f);
  float off = __fmul_rn((float)l, maxc);
  const float4* lbox = (const float4*)(ws + LBOX_OFF) + (size_t)P * 1024;
  float4 bi = lbox[i];
  bi.x = __fadd_rn(bi.x, off); bi.y = __fadd_rn(bi.y, off);
  bi.z = __fadd_rn(bi.z, off); bi.w = __fadd_rn(bi.w, off);
  float ai = __fmul_rn(__fsub_rn(bi.z, bi.x), __fsub_rn(bi.w, bi.y));
  u64 word = 0;
  int j0 = w << 6;
  int jn = min(64, n - j0);
  for (int jj = 0; jj < jn; ++jj) {
    float4 bj = lbox[j0 + jj];
    bj.x = __fadd_rn(bj.x, off); bj.y = __fadd_rn(bj.y, off);
    bj.z = __fadd_rn(bj.z, off); bj.w = __fadd_rn(bj.w, off);
    float xx1 = fmaxf(bi.x, bj.x);
    float yy1 = fmaxf(bi.y, bj.y);
    float xx2 = fminf(bi.z, bj.z);
    float yy2 = fminf(bi.w, bj.w);
    float iw = fmaxf(__fsub_rn(xx2, xx1), 0.0f);
    float ih = fmaxf(__fsub_rn(yy2, yy1), 0.0f);
    float inter = __fmul_rn(iw, ih);
    float aj = __fmul_rn(__fsub_rn(bj.z, bj.x), __fsub_rn(bj.w, bj.y));
    float den = __fadd_rn(__fsub_rn(__fadd_rn(ai, aj), inter), 1e-9f);
    float iou = __fdiv_rn(inter, den);
    if (iou > 0.7f) word |= (1ull << jj);
  }
  if (i >= j0 && i < j0 + 64) word &= ~(1ull << (i - j0));   // zero diagonal
  ((u64*)(ws + MASK_OFF))[(size_t)P * 16000 + (size_t)i * W + w] = word;
  if (word)
    atomicOr((u64*)(ws + CHUNKANY_OFF) + (size_t)P * 16 + (i >> 6), 1ull << (i & 63));
}

// ---------- 6) NMS scan (5 waves = 5 levels), latency-optimized + parallel emit ----------
__global__ __launch_bounds__(320)
void k_scanfin(float* __restrict__ out, char* __restrict__ ws) {
  __shared__ u64 keeps[5][16];
  __shared__ u64 kb[80];
  __shared__ u32 sb[128];
  __shared__ u32 pfx[80];
  __shared__ u32 nvs[5];
  int tid = threadIdx.x, w = tid >> 6, lane = tid & 63;
  int b = blockIdx.x;
  for (int i = tid; i < 80; i += 320) kb[i] = 0ull;
  for (int i = tid; i < 4000; i += 320) out[(size_t)b * 4000 + i] = 0.0f;
  for (int i = tid; i < 1000; i += 320) out[8000 + (size_t)b * 1000 + i] = 0.0f;
  if (tid < 5) nvs[tid] = ((const u32*)(ws + NV_OFF))[b * 5 + tid];

  int P = b * 5 + w;
  int n = (int)((const u32*)(ws + NV_OFF))[P];
  int W = (n + 63) >> 6;
  const u64* maskg = (const u64*)(ws + MASK_OFF) + (size_t)P * 16000;
  // prefetch chunkany (1 load) and all diag words (burst of <=16 independent loads)
  u64 ca = (lane < 16) ? ((const u64*)(ws + CHUNKANY_OFF))[(size_t)P * 16 + lane] : 0ull;
  u64 dpre[16];
#pragma unroll
  for (int c = 0; c < 16; ++c) {
    int row = (c << 6) + lane;
    dpre[c] = (c < W && row < n) ? maskg[(size_t)row * W + c] : 0ull;
  }
  u64 removed = 0ull, keepw = 0ull;
#pragma unroll
  for (int c = 0; c < 16; ++c) {
    if (c >= W) break;
    int rb = c << 6;
    int rows = min(64, n - rb);
    u64 rowsmask = (rows == 64) ? ~0ull : ((1ull << rows) - 1ull);
    u64 curw = __shfl(removed, c);
    u64 cand = ~curw & rowsmask;
    u64 ca_c = __shfl(ca, c);
    u64 keptbits;
    u64 anyrows = ca_c & cand;
    if (anyrows == 0ull) {
      keptbits = cand;
    } else {
      u64 diag = dpre[c];
      u64 diagnz = __ballot(diag != 0ull) & cand;
      if (diagnz == 0ull) {
        keptbits = cand;
      } else {
        // sparse serial chain: only rows with nonzero diag need sequencing
        u64 remw = curw | ~rowsmask;
        u64 kept = 0ull;
        int pos = 0;
        u64 work = diagnz;
        while (work) {
          int s = __builtin_ctzll(work); work &= work - 1;
          u64 range = (1ull << s) - (1ull << pos);   // bits pos..s-1
          kept |= ~remw & range;                      // zero-diag rows: kept iff alive
          bool k = ((remw >> s) & 1ull) == 0ull;      // uniform across lanes
          u64 dr = __shfl(diag, s);
          if (k) { kept |= 1ull << s; remw |= dr; }
          pos = s + 1;
        }
        u64 tail = (pos >= 64) ? 0ull : (~0ull << pos);
        kept |= ~remw & tail & rowsmask;
        keptbits = kept;
      }
      // cross-chunk OR of kept rows with any bits, batched x4 (independent loads)
      u64 todo = keptbits & ca_c;
      while (todo) {
        int r0 = __builtin_ctzll(todo); todo &= todo - 1;
        int r1 = -1, r2 = -1, r3 = -1;
        if (todo) { r1 = __builtin_ctzll(todo); todo &= todo - 1; }
        if (todo) { r2 = __builtin_ctzll(todo); todo &= todo - 1; }
        if (todo) { r3 = __builtin_ctzll(todo); todo &= todo - 1; }
        u64 v0 = 0, v1 = 0, v2 = 0, v3 = 0;
        if (lane < W) {
          v0 = maskg[(size_t)(rb + r0) * W + lane];
          if (r1 >= 0) v1 = maskg[(size_t)(rb + r1) * W + lane];
          if (r2 >= 0) v2 = maskg[(size_t)(rb + r2) * W + lane];
          if (r3 >= 0) v3 = maskg[(size_t)(rb + r3) * W + lane];
        }
        removed |= v0 | v1 | v2 | v3;
      }
    }
    if (lane == c) keepw |= keptbits;
  }
  if (lane < 16) keeps[w][lane] = keepw;
  __syncthreads();

  // build rank bitmap (parallel)
  const u32* rank = (const u32*)(ws + RANK_OFF);
  for (int idx = tid; idx < 5120; idx += 320) {
    int p = idx >> 10, i = idx & 1023;
    if (i < (int)nvs[p] && ((keeps[p][i >> 6] >> (i & 63)) & 1ull)) {
      u32 r = rank[(size_t)(b * 5 + p) * 1024 + i];
      atomicOr(&kb[r >> 6], 1ull << (r & 63));
    }
  }
  __syncthreads();
  // exclusive prefix of popcounts over 80 words (Hillis-Steele, 128-wide)
  if (tid < 128) sb[tid] = (tid < 80) ? (u32)__popcll(kb[tid]) : 0u;
  __syncthreads();
  for (int d = 1; d < 128; d <<= 1) {
    u32 x = (tid < 128 && tid >= d) ? sb[tid - d] : 0u;
    __syncthreads();
    if (tid < 128) sb[tid] += x;
    __syncthreads();
  }
  if (tid < 80) pfx[tid] = sb[tid] - (u32)__popcll(kb[tid]);
  __syncthreads();
  // parallel emit
  for (int idx = tid; idx < 5120; idx += 320) {
    int p = idx >> 10, i = idx & 1023;
    if (i < (int)nvs[p] && ((keeps[p][i >> 6] >> (i & 63)) & 1ull)) {
      int Pp = b * 5 + p;
      u32 r = rank[(size_t)Pp * 1024 + i];
      u64 word = kb[r >> 6];
      int slot = (int)pfx[r >> 6] + __popcll(word & ((1ull << (r & 63)) - 1ull));
      if (slot < KTOP) {
        float4 bx = ((const float4*)(ws + LBOX_OFF))[(size_t)Pp * 1024 + i];
        float s = ((const float*)(ws + LSC_OFF))[(size_t)Pp * 1024 + i];
        float* ob = out + ((size_t)b * KTOP + slot) * 4;
        ob[0] = bx.x; ob[1] = bx.y; ob[2] = bx.z; ob[3] = bx.w;
        out[8000 + (size_t)b * KTOP + slot] = s;
      }
    }
  }
}

extern "C" void kernel_launch(void* const* d_in, const int* in_sizes, int n_in,
                              void* d_out, int out_size, void* d_ws, size_t ws_size,
                              hipStream_t stream) {
  const float* pred = (const float*)d_in[0];
  const float* obj  = (const float*)d_in[1];
  const float* anch = (const float*)d_in[2];
  const float* vs   = (const float*)d_in[3];
  float* out = (float*)d_out;
  char* ws = (char*)d_ws;
  (void)in_sizes; (void)n_in; (void)out_size; (void)ws_size;

  int gZ = (int)((ZERO_END / 4 + 255) / 256);
  k_zero      <<<gZ,        256, 0, stream>>>(ws);
  k_hist12    <<<BS * NBH,  256, 0, stream>>>(obj, ws);
  k_compactsel<<<BS * NBH,  256, 0, stream>>>(obj, ws);
  k_sortdec   <<<10,        256, 0, stream>>>(pred, obj, anch, vs, ws);
  k_maskrank  <<<640,       256, 0, stream>>>(ws);
  k_scanfin   <<<2,         320, 0, stream>>>(out, ws);
}

// Round 9
// 173.279 us; speedup vs baseline: 3.1035x; 1.1182x over previous
//
#include <hip/hip_runtime.h>

typedef unsigned int u32;
typedef unsigned long long u64;

#define A_TOT    159882
#define BS       2
#define KTOP     1000
#define CAND_CAP 4096
#define HB       4096        // 12-bit histogram buckets per segment
#define ABLK     4096        // anchors per hist/compact block
#define NBH      40          // blocks per image (40*4096 >= A_TOT)
#define EPT      16          // ABLK/256

// ---- workspace layout (bytes) ----
static const size_t HIST12_OFF   = 0;         // u32[8*4096] = 128 KB (L2-resident)
static const size_t CUT_OFF      = 131072;    // u32[8]
static const size_t CCNT_OFF     = 131104;    // u32[8]
static const size_t MAXC_OFF     = 131136;    // u32[2]
static const size_t NV_OFF       = 131144;    // u32[10]
static const size_t CHUNKANY_OFF = 131200;    // u64[10*16]
static const size_t ZERO_END     = 132480;    // k_zero covers [0, ZERO_END)
static const size_t CAND_OFF     = 132480;    // u64[8*4096]
static const size_t LKEY2_OFF    = 394624;    // u64[10*1024]
static const size_t LBOX_OFF     = 476544;    // float4[10*1024]
static const size_t LSC_OFF      = 640384;    // float[10*1024]
static const size_t RANK_OFF     = 681344;    // u32[10*1024]
static const size_t MASK_OFF     = 759168;    // u64[10*16000]
// total ~2.04 MB

__device__ __forceinline__ int level_of(int a) {
  if (a < 120000) return 0;
  if (a < 150000) return 1;
  if (a < 157500) return 2;
  if (a < 159375) return 3;
  return 4;
}

// monotone decreasing transform: smaller d == larger score; d(-inf)=0xFF800000
__device__ __forceinline__ u32 dkey(float s) {
  u32 b = __float_as_uint(s);
  return (b & 0x80000000u) ? b : (~b & 0x7FFFFFFFu);
}
// exact inverse of dkey
__device__ __forceinline__ float dkey_inv(u32 d) {
  u32 b = (d & 0x80000000u) ? d : (~d & 0x7FFFFFFFu);
  return __uint_as_float(b);
}

// bit-exact replica of reference decode + clip + min-size check
__device__ __forceinline__ void decode_clip(const float* __restrict__ pred,
                                            const float* __restrict__ anch,
                                            const float* __restrict__ vs,
                                            int b, int a,
                                            float& x1c, float& y1c, float& x2c, float& y2c,
                                            bool& valid) {
  const float* pp = pred + ((size_t)b * A_TOT + (size_t)a) * 4;
  const float* aa = anch + (size_t)a * 4;
  float ax1 = aa[0], ay1 = aa[1], ax2 = aa[2], ay2 = aa[3];
  float px = pp[0], py = pp[1], pw = pp[2], ph = pp[3];
  float aw  = __fsub_rn(ax2, ax1);
  float ah  = __fsub_rn(ay2, ay1);
  float acx = __fadd_rn(ax1, __fmul_rn(0.5f, aw));
  float acy = __fadd_rn(ay1, __fmul_rn(0.5f, ah));
  float cx  = __fadd_rn(acx, __fmul_rn(px, aw));
  float cy  = __fadd_rn(acy, __fmul_rn(py, ah));
  float w   = __fmul_rn(expf(pw), aw);
  float h   = __fmul_rn(expf(ph), ah);
  float x1  = __fsub_rn(cx, __fmul_rn(0.5f, w));
  float y1  = __fsub_rn(cy, __fmul_rn(0.5f, h));
  float x2  = __fadd_rn(x1, w);
  float y2  = __fadd_rn(y1, h);
  float Wv = vs[b * 2 + 0], Hv = vs[b * 2 + 1];
  x1c = fminf(fmaxf(x1, 0.0f), Wv);
  y1c = fminf(fmaxf(y1, 0.0f), Hv);
  x2c = fminf(fmaxf(x2, 0.0f), Wv);
  y2c = fminf(fmaxf(y2, 0.0f), Hv);
  valid = (__fsub_rn(x2c, x1c) > 0.001f) && (__fsub_rn(y2c, y1c) > 0.001f);
}

__device__ __forceinline__ void bitonic_u64(u64* arr, int N, int t, int nt) {
  for (int k = 2; k <= N; k <<= 1) {
    for (int j = k >> 1; j > 0; j >>= 1) {
      __syncthreads();
      for (int i = t; i < N; i += nt) {
        int ixj = i ^ j;
        if (ixj > i) {
          u64 x = arr[i], y = arr[ixj];
          bool up = ((i & k) == 0);
          if (up ? (x > y) : (x < y)) { arr[i] = y; arr[ixj] = x; }
        }
      }
    }
  }
  __syncthreads();
}

__device__ __forceinline__ u64 shfl_xor_u64(u64 x, int lanemask) {
  u32 lo = (u32)x, hi = (u32)(x >> 32);
  lo = (u32)__shfl_xor((int)lo, lanemask);
  hi = (u32)__shfl_xor((int)hi, lanemask);
  return ((u64)hi << 32) | (u64)lo;
}

// bitonic sort of 2048 u64 keys: 2/thread over 1024 threads.
// j==1: in-register; 2<=j<=64: wave shuffle; j>=128: LDS double-buffered
// (one sync per LDS phase). Returns pointer to sorted LDS buffer.
__device__ __forceinline__ u64* regsort2048x(u64 v[2], int tid, u64* bufA, u64* bufB) {
  u64* bufs[2] = {bufA, bufB};
  int cur = 0;
  for (int k = 2; k <= 2048; k <<= 1) {
    for (int j = k >> 1; j > 0; j >>= 1) {
      if (j == 1) {
        bool up = (((2 * tid) & k) == 0);
        u64 a = v[0], b2 = v[1];
        bool sw = up ? (a > b2) : (a < b2);
        if (sw) { v[0] = b2; v[1] = a; }
      } else if (j <= 64) {
        int dl = j >> 1;
        bool up = (((2 * tid) & k) == 0);
        bool low = ((tid & dl) == 0);
        bool keepmin = (low == up);
#pragma unroll
        for (int e = 0; e < 2; ++e) {
          u64 o = shfl_xor_u64(v[e], dl);
          v[e] = keepmin ? (v[e] < o ? v[e] : o) : (v[e] > o ? v[e] : o);
        }
      } else {
        u64* B = bufs[cur]; cur ^= 1;
        B[2 * tid] = v[0]; B[2 * tid + 1] = v[1];
        __syncthreads();
#pragma unroll
        for (int e = 0; e < 2; ++e) {
          int i = 2 * tid + e, p = i ^ j;
          u64 o = B[p];
          bool up = ((i & k) == 0);
          bool keepmin = ((i < p) == up);
          v[e] = keepmin ? (v[e] < o ? v[e] : o) : (v[e] > o ? v[e] : o);
        }
      }
    }
  }
  u64* B = bufs[cur];
  B[2 * tid] = v[0]; B[2 * tid + 1] = v[1];
  __syncthreads();
  return B;
}

// ---------- 1) zero control + histogram region ----------
__global__ void k_zero(char* __restrict__ ws) {
  size_t i = (size_t)blockIdx.x * blockDim.x + threadIdx.x;
  if (i * 4 < ZERO_END) ((u32*)ws)[i] = 0u;
}

// ---------- 2) 12-bit histogram, LDS-privatized (<=2 segments/block) ----------
__global__ void k_hist12(const float* __restrict__ obj, char* __restrict__ ws) {
  __shared__ u32 h[2 * HB];   // 32 KB
  int tid = threadIdx.x;
  int b = blockIdx.x / NBH, loc = blockIdx.x % NBH;
  int start = loc * ABLK;
  int l0 = level_of(start);
  if (l0 >= 4) return;
  for (int i = tid; i < 2 * HB; i += 256) h[i] = 0u;
  __syncthreads();
  for (int it = 0; it < EPT; ++it) {
    int a = start + it * 256 + tid;
    if (a < A_TOT) {
      int l = level_of(a);
      if (l < 4) {
        u32 d = dkey(obj[(size_t)b * A_TOT + a]);
        atomicAdd(&h[(u32)(l - l0) * HB + (d >> 20)], 1u);
      }
    }
  }
  __syncthreads();
  int lend = level_of(min(start + ABLK - 1, A_TOT - 1));
  int nseg = ((l0 + 1 <= lend) && (l0 + 1 < 4)) ? 2 : 1;
  for (int s = 0; s < nseg; ++s) {
    u32* gh = (u32*)(ws + HIST12_OFF) + (size_t)(b * 4 + l0 + s) * HB;
    for (int i = tid; i < HB; i += 256) {
      u32 v = h[s * HB + i];
      if (v) atomicAdd(&gh[i], v);
    }
  }
}

// ---------- 3) inline cutoff + block-aggregated candidate append ----------
__global__ void k_compactsel(const float* __restrict__ obj, char* __restrict__ ws) {
  __shared__ u32 scan[256];
  __shared__ u32 cutv[2];
  __shared__ u32 lcnt[2], gbase[2];
  int tid = threadIdx.x, lane = tid & 63;
  int b = blockIdx.x / NBH, loc = blockIdx.x % NBH;
  int start = loc * ABLK;
  int l0 = level_of(start);
  if (l0 >= 4) return;
  int lend = level_of(min(start + ABLK - 1, A_TOT - 1));
  int nseg = ((l0 + 1 <= lend) && (l0 + 1 < 4)) ? 2 : 1;
  if (tid < 2) lcnt[tid] = 0;
  // recompute segment cutoffs from L2-resident hist (idempotent across blocks)
  for (int s = 0; s < nseg; ++s) {
    int seg = b * 4 + l0 + s;
    const u32* gh = (const u32*)(ws + HIST12_OFF) + (size_t)seg * HB;
    u32 vals[16]; u32 acc = 0;
    for (int q = 0; q < 16; ++q) { vals[q] = gh[tid * 16 + q]; acc += vals[q]; }
    __syncthreads();
    scan[tid] = acc; __syncthreads();
    for (int d = 1; d < 256; d <<= 1) {
      u32 x = (tid >= d) ? scan[tid - d] : 0u; __syncthreads();
      scan[tid] += x; __syncthreads();
    }
    u32 incl = scan[tid], prev = incl - acc;
    if (prev < KTOP && incl >= KTOP) {
      u32 run = prev; int cb = HB - 1;
      for (int q = 0; q < 16; ++q) { run += vals[q]; if (run >= KTOP) { cb = tid * 16 + q; break; } }
      cutv[s] = (u32)cb;
      ((u32*)(ws + CUT_OFF))[seg] = (u32)cb;
    }
  }
  __syncthreads();
  u32 dv[EPT], slotv[EPT], passm = 0, sim = 0;
  for (int it = 0; it < EPT; ++it) {
    int a = start + it * 256 + tid;
    bool pass = false; u32 si = 0, d = 0;
    if (a < A_TOT) {
      int l = level_of(a);
      if (l < 4) {
        si = (u32)(l - l0);
        d = dkey(obj[(size_t)b * A_TOT + a]);
        pass = (d >> 20) <= cutv[si];
      }
    }
    dv[it] = d;
    u64 mp = __ballot(pass);
    u64 m1 = __ballot(pass && si == 1);
    u64 m0 = mp & ~m1;
    u32 slot = 0;
    if (m0) {
      int ld = __builtin_ctzll(m0);
      u32 wb = 0;
      if (lane == ld) wb = atomicAdd(&lcnt[0], (u32)__popcll(m0));
      wb = __shfl(wb, ld);
      if (pass && si == 0) slot = wb + (u32)__popcll(m0 & ((1ull << lane) - 1ull));
    }
    if (m1) {
      int ld = __builtin_ctzll(m1);
      u32 wb = 0;
      if (lane == ld) wb = atomicAdd(&lcnt[1], (u32)__popcll(m1));
      wb = __shfl(wb, ld);
      if (pass && si == 1) slot = wb + (u32)__popcll(m1 & ((1ull << lane) - 1ull));
    }
    slotv[it] = slot;
    if (pass) { passm |= 1u << it; if (si) sim |= 1u << it; }
  }
  __syncthreads();
  if (tid < 2)
    gbase[tid] = lcnt[tid] ? atomicAdd((u32*)(ws + CCNT_OFF) + (b * 4 + l0 + tid), lcnt[tid]) : 0u;
  __syncthreads();
  for (int it = 0; it < EPT; ++it) {
    if ((passm >> it) & 1u) {
      int a = start + it * 256 + tid;
      u32 si = (sim >> it) & 1u;
      int seg = b * 4 + l0 + (int)si;
      u32 gslot = gbase[si] + slotv[it];
      if (gslot < CAND_CAP)
        // key = [dkey:32][anchor:18][slot:12] — slot below the anchor tie-break
        ((u64*)(ws + CAND_OFF))[(size_t)seg * CAND_CAP + gslot] =
            ((u64)dv[it] << 32) | ((u64)(u32)a << 12) | (u64)gslot;
    }
  }
}

// ---------- 4) per-(image,level): parallel gather-decode + register bitonic + compaction ----------
__global__ __launch_bounds__(1024)
void k_sortdec(const float* __restrict__ pred, const float* __restrict__ obj,
               const float* __restrict__ anch, const float* __restrict__ vs,
               char* __restrict__ ws) {
  __shared__ u64 bufAB[4096];        // 32 KB (double buffer / fallback array)
  __shared__ float4 dboxS[2048];     // 32 KB, indexed by slot
  __shared__ float dscS[2048];       // 8 KB
  __shared__ u32 validS[2048];       // 8 KB
  __shared__ u64 cm[16];
  u64* bufA = bufAB; u64* bufB = bufAB + 2048;
  int tid = threadIdx.x, lane = tid & 63, wv = tid >> 6;
  int P = blockIdx.x, b = P / 5, l = P % 5;
  int n;
  u64* S;
  if (l == 4) {
    n = 507;
    u64 v[2];
#pragma unroll
    for (int e = 0; e < 2; ++e) {
      int idx = 2 * tid + e;
      if (idx < 507) {
        int a = 159375 + idx;
        float sc = obj[(size_t)b * A_TOT + a];
        float x1, y1, x2, y2; bool valid;
        decode_clip(pred, anch, vs, b, a, x1, y1, x2, y2, valid);
        dboxS[idx] = make_float4(x1, y1, x2, y2);
        dscS[idx] = sc;
        validS[idx] = valid ? 1u : 0u;
        v[e] = ((u64)dkey(sc) << 32) | ((u64)(u32)a << 12) | (u64)idx;
      } else v[e] = ~0ull;
    }
    S = regsort2048x(v, tid, bufA, bufB);
  } else {
    n = KTOP;
    int seg = b * 4 + l;
    u32 cnt = min(((const u32*)(ws + CCNT_OFF))[seg], (u32)CAND_CAP);
    const u64* cand = (const u64*)(ws + CAND_OFF) + (size_t)seg * CAND_CAP;
    if (cnt <= 2048) {
      u64 v[2];
#pragma unroll
      for (int e = 0; e < 2; ++e) {
        int idx = 2 * tid + e;
        if (idx < (int)cnt) {
          u64 key = cand[idx];
          int a = (int)((key >> 12) & 0x3FFFFu);
          float x1, y1, x2, y2; bool valid;
          decode_clip(pred, anch, vs, b, a, x1, y1, x2, y2, valid);
          dboxS[idx] = make_float4(x1, y1, x2, y2);
          dscS[idx] = dkey_inv((u32)(key >> 32));
          validS[idx] = valid ? 1u : 0u;
          v[e] = key;
        } else v[e] = ~0ull;
      }
      S = regsort2048x(v, tid, bufA, bufB);
    } else {
      // safety fallback (statistically never taken: cnt ~= 1030)
      int N = 2048; while (N < (int)cnt) N <<= 1;
      for (int i = tid; i < N; i += 1024) bufAB[i] = (i < (int)cnt) ? cand[i] : ~0ull;
      bitonic_u64(bufAB, N, tid, 1024);
      for (int j = tid; j < KTOP; j += 1024) {
        u64 key = bufAB[j];
        int a = (int)((key >> 12) & 0x3FFFFu);
        float x1, y1, x2, y2; bool valid;
        decode_clip(pred, anch, vs, b, a, x1, y1, x2, y2, valid);
        dboxS[j] = make_float4(x1, y1, x2, y2);
        dscS[j] = dkey_inv((u32)(key >> 32));
        validS[j] = valid ? 1u : 0u;
        bufAB[j] = (key & ~0xFFFull) | (u64)j;   // rewrite slot = sorted pos
      }
      __syncthreads();
      S = bufAB;
    }
  }
  // max coord over the selected top-n (reference: max over selected boxes only)
  float m = 0.0f;
  for (int j = tid; j < n; j += 1024) {
    int slot = (int)(S[j] & 0xFFFull);
    float4 bx = dboxS[slot];
    m = fmaxf(m, fmaxf(fmaxf(bx.x, bx.y), fmaxf(bx.z, bx.w)));
  }
  for (int off = 32; off; off >>= 1) m = fmaxf(m, __shfl_xor(m, off));
  if (lane == 0) atomicMax((u32*)(ws + MAXC_OFF) + b, __float_as_uint(m));
  // stable valid-compaction, all 16 waves (wave w owns chunk w of 64)
  {
    int j = wv * 64 + lane;
    bool val = (j < n) && (validS[(int)(S[j] & 0xFFFull)] != 0u);
    u64 mask = __ballot(val);
    if (lane == 0) cm[wv] = mask;
    __syncthreads();
    int base = 0;
    for (int w2 = 0; w2 < wv; ++w2) base += __popcll(cm[w2]);
    if (val) {
      int r = base + __popcll(mask & ((1ull << lane) - 1ull));
      int slot = (int)(S[j] & 0xFFFull);
      ((u64*)(ws + LKEY2_OFF))[(size_t)P * 1024 + r] = S[j];
      ((float4*)(ws + LBOX_OFF))[(size_t)P * 1024 + r] = dboxS[slot];
      ((float*)(ws + LSC_OFF))[(size_t)P * 1024 + r] = dscS[slot];
    }
    if (tid == 0) {
      int tot = 0;
      for (int w2 = 0; w2 < 16; ++w2) tot += __popcll(cm[w2]);
      ((u32*)(ws + NV_OFF))[P] = (u32)tot;
    }
  }
}

__device__ __forceinline__ int lbound(const u64* __restrict__ arr, int n, u64 key) {
  int lo = 0, hi = n;
  while (lo < hi) { int mid = (lo + hi) >> 1; if (arr[mid] < key) lo = mid + 1; else hi = mid; }
  return lo;
}

// ---------- 5) rank (blocks 0-9) + suppression bitmask (all blocks) ----------
__global__ void k_maskrank(char* __restrict__ ws) {
  int tid = threadIdx.x, bid = blockIdx.x;
  if (bid < 10) {
    int P = bid, b = P / 5, l = P % 5;
    int nv = (int)((const u32*)(ws + NV_OFF))[P];
    const u64* lkey = (const u64*)(ws + LKEY2_OFF);
    const u32* nvp = (const u32*)(ws + NV_OFF);
    for (int i = tid; i < nv; i += 256) {
      u64 key = lkey[(size_t)P * 1024 + i];
      int r = i;
      for (int l2 = 0; l2 < 5; ++l2) {
        if (l2 == l) continue;
        int P2 = b * 5 + l2;
        r += lbound(lkey + (size_t)P2 * 1024, (int)nvp[P2], key);
      }
      ((u32*)(ws + RANK_OFF))[(size_t)P * 1024 + i] = (u32)r;
    }
  }
  int idx = bid * 256 + tid;       // 640*256 = 163840 items
  int w = idx & 15;
  int i = (idx >> 4) & 1023;
  int P = idx >> 14;
  if (P >= 10) return;
  int b = P / 5, l = P % 5;
  int n = (int)((const u32*)(ws + NV_OFF))[P];
  int W = (n + 63) >> 6;
  if (i >= n || w >= W) return;
  float M = __uint_as_float(((const u32*)(ws + MAXC_OFF))[b]);
  float maxc = __fadd_rn(M, 1.0f);
  float off = __fmul_rn((float)l, maxc);
  const float4* lbox = (const float4*)(ws + LBOX_OFF) + (size_t)P * 1024;
  float4 bi = lbox[i];
  bi.x = __fadd_rn(bi.x, off); bi.y = __fadd_rn(bi.y, off);
  bi.z = __fadd_rn(bi.z, off); bi.w = __fadd_rn(bi.w, off);
  float ai = __fmul_rn(__fsub_rn(bi.z, bi.x), __fsub_rn(bi.w, bi.y));
  u64 word = 0;
  int j0 = w << 6;
  int jn = min(64, n - j0);
  for (int jj = 0; jj < jn; ++jj) {
    float4 bj = lbox[j0 + jj];
    bj.x = __fadd_rn(bj.x, off); bj.y = __fadd_rn(bj.y, off);
    bj.z = __fadd_rn(bj.z, off); bj.w = __fadd_rn(bj.w, off);
    float xx1 = fmaxf(bi.x, bj.x);
    float yy1 = fmaxf(bi.y, bj.y);
    float xx2 = fminf(bi.z, bj.z);
    float yy2 = fminf(bi.w, bj.w);
    float iw = fmaxf(__fsub_rn(xx2, xx1), 0.0f);
    float ih = fmaxf(__fsub_rn(yy2, yy1), 0.0f);
    float inter = __fmul_rn(iw, ih);
    float aj = __fmul_rn(__fsub_rn(bj.z, bj.x), __fsub_rn(bj.w, bj.y));
    float den = __fadd_rn(__fsub_rn(__fadd_rn(ai, aj), inter), 1e-9f);
    float iou = __fdiv_rn(inter, den);
    if (iou > 0.7f) word |= (1ull << jj);
  }
  if (i >= j0 && i < j0 + 64) word &= ~(1ull << (i - j0));   // zero diagonal
  ((u64*)(ws + MASK_OFF))[(size_t)P * 16000 + (size_t)i * W + w] = word;
  if (word)
    atomicOr((u64*)(ws + CHUNKANY_OFF) + (size_t)P * 16 + (i >> 6), 1ull << (i & 63));
}

// ---------- 6) NMS scan (5 waves = 5 levels), latency-optimized + parallel emit ----------
__global__ __launch_bounds__(320)
void k_scanfin(float* __restrict__ out, char* __restrict__ ws) {
  __shared__ u64 keeps[5][16];
  __shared__ u64 kb[80];
  __shared__ u32 sb[128];
  __shared__ u32 pfx[80];
  __shared__ u32 nvs[5];
  int tid = threadIdx.x, w = tid >> 6, lane = tid & 63;
  int b = blockIdx.x;
  for (int i = tid; i < 80; i += 320) kb[i] = 0ull;
  for (int i = tid; i < 4000; i += 320) out[(size_t)b * 4000 + i] = 0.0f;
  for (int i = tid; i < 1000; i += 320) out[8000 + (size_t)b * 1000 + i] = 0.0f;
  if (tid < 5) nvs[tid] = ((const u32*)(ws + NV_OFF))[b * 5 + tid];

  int P = b * 5 + w;
  int n = (int)((const u32*)(ws + NV_OFF))[P];
  int W = (n + 63) >> 6;
  const u64* maskg = (const u64*)(ws + MASK_OFF) + (size_t)P * 16000;
  u64 ca = (lane < 16) ? ((const u64*)(ws + CHUNKANY_OFF))[(size_t)P * 16 + lane] : 0ull;
  u64 dpre[16];
#pragma unroll
  for (int c = 0; c < 16; ++c) {
    int row = (c << 6) + lane;
    dpre[c] = (c < W && row < n) ? maskg[(size_t)row * W + c] : 0ull;
  }
  u64 removed = 0ull, keepw = 0ull;
#pragma unroll
  for (int c = 0; c < 16; ++c) {
    if (c >= W) break;
    int rb = c << 6;
    int rows = min(64, n - rb);
    u64 rowsmask = (rows == 64) ? ~0ull : ((1ull << rows) - 1ull);
    u64 curw = __shfl(removed, c);
    u64 cand = ~curw & rowsmask;
    u64 ca_c = __shfl(ca, c);
    u64 keptbits;
    u64 anyrows = ca_c & cand;
    if (anyrows == 0ull) {
      keptbits = cand;
    } else {
      u64 diag = dpre[c];
      u64 diagnz = __ballot(diag != 0ull) & cand;
      if (diagnz == 0ull) {
        keptbits = cand;
      } else {
        u64 remw = curw | ~rowsmask;
        u64 kept = 0ull;
        int pos = 0;
        u64 work = diagnz;
        while (work) {
          int s = __builtin_ctzll(work); work &= work - 1;
          u64 range = (1ull << s) - (1ull << pos);
          kept |= ~remw & range;
          bool k = ((remw >> s) & 1ull) == 0ull;
          u64 dr = __shfl(diag, s);
          if (k) { kept |= 1ull << s; remw |= dr; }
          pos = s + 1;
        }
        u64 tail = (pos >= 64) ? 0ull : (~0ull << pos);
        kept |= ~remw & tail & rowsmask;
        keptbits = kept;
      }
      u64 todo = keptbits & ca_c;
      while (todo) {
        int r0 = __builtin_ctzll(todo); todo &= todo - 1;
        int r1 = -1, r2 = -1, r3 = -1;
        if (todo) { r1 = __builtin_ctzll(todo); todo &= todo - 1; }
        if (todo) { r2 = __builtin_ctzll(todo); todo &= todo - 1; }
        if (todo) { r3 = __builtin_ctzll(todo); todo &= todo - 1; }
        u64 v0 = 0, v1 = 0, v2 = 0, v3 = 0;
        if (lane < W) {
          v0 = maskg[(size_t)(rb + r0) * W + lane];
          if (r1 >= 0) v1 = maskg[(size_t)(rb + r1) * W + lane];
          if (r2 >= 0) v2 = maskg[(size_t)(rb + r2) * W + lane];
          if (r3 >= 0) v3 = maskg[(size_t)(rb + r3) * W + lane];
        }
        removed |= v0 | v1 | v2 | v3;
      }
    }
    if (lane == c) keepw |= keptbits;
  }
  if (lane < 16) keeps[w][lane] = keepw;
  __syncthreads();

  const u32* rank = (const u32*)(ws + RANK_OFF);
  for (int idx = tid; idx < 5120; idx += 320) {
    int p = idx >> 10, i = idx & 1023;
    if (i < (int)nvs[p] && ((keeps[p][i >> 6] >> (i & 63)) & 1ull)) {
      u32 r = rank[(size_t)(b * 5 + p) * 1024 + i];
      atomicOr(&kb[r >> 6], 1ull << (r & 63));
    }
  }
  __syncthreads();
  if (tid < 128) sb[tid] = (tid < 80) ? (u32)__popcll(kb[tid]) : 0u;
  __syncthreads();
  for (int d = 1; d < 128; d <<= 1) {
    u32 x = (tid < 128 && tid >= d) ? sb[tid - d] : 0u;
    __syncthreads();
    if (tid < 128) sb[tid] += x;
    __syncthreads();
  }
  if (tid < 80) pfx[tid] = sb[tid] - (u32)__popcll(kb[tid]);
  __syncthreads();
  for (int idx = tid; idx < 5120; idx += 320) {
    int p = idx >> 10, i = idx & 1023;
    if (i < (int)nvs[p] && ((keeps[p][i >> 6] >> (i & 63)) & 1ull)) {
      int Pp = b * 5 + p;
      u32 r = rank[(size_t)Pp * 1024 + i];
      u64 word = kb[r >> 6];
      int slot = (int)pfx[r >> 6] + __popcll(word & ((1ull << (r & 63)) - 1ull));
      if (slot < KTOP) {
        float4 bx = ((const float4*)(ws + LBOX_OFF))[(size_t)Pp * 1024 + i];
        float s = ((const float*)(ws + LSC_OFF))[(size_t)Pp * 1024 + i];
        float* ob = out + ((size_t)b * KTOP + slot) * 4;
        ob[0] = bx.x; ob[1] = bx.y; ob[2] = bx.z; ob[3] = bx.w;
        out[8000 + (size_t)b * KTOP + slot] = s;
      }
    }
  }
}

extern "C" void kernel_launch(void* const* d_in, const int* in_sizes, int n_in,
                              void* d_out, int out_size, void* d_ws, size_t ws_size,
                              hipStream_t stream) {
  const float* pred = (const float*)d_in[0];
  const float* obj  = (const float*)d_in[1];
  const float* anch = (const float*)d_in[2];
  const float* vs   = (const float*)d_in[3];
  float* out = (float*)d_out;
  char* ws = (char*)d_ws;
  (void)in_sizes; (void)n_in; (void)out_size; (void)ws_size;

  int gZ = (int)((ZERO_END / 4 + 255) / 256);
  k_zero      <<<gZ,        256, 0, stream>>>(ws);
  k_hist12    <<<BS * NBH,  256, 0, stream>>>(obj, ws);
  k_compactsel<<<BS * NBH,  256, 0, stream>>>(obj, ws);
  k_sortdec   <<<10,       1024, 0, stream>>>(pred, obj, anch, vs, ws);
  k_maskrank  <<<640,       256, 0, stream>>>(ws);
  k_scanfin   <<<2,         320, 0, stream>>>(out, ws);
}